// Round 5
// baseline (810.315 us; speedup 1.0000x reference)
//
#include <hip/hip_runtime.h>
#include <math.h>

// ---------------------------------------------------------------------------
// NormDist (Lp, p=8) IBP AlexNet. Round 5: transposed weights (coalesced
// lane=o weight loads), merged blocks (one LDS staging per slab), o-fastest
// coalesced partial stores + layout-fixing combines, transposed-weight FC.
// lp8(d) = (sum d^8)^(1/8); relu after conv = no-op (norms >= 0).
// ---------------------------------------------------------------------------

__device__ __forceinline__ float rt8(float s) { return sqrtf(sqrtf(sqrtf(s))); }

__device__ __forceinline__ void tap16(float w, float pc, float pl, float pu,
                                      float& aC, float& aL, float& aH)
{
    float a = pc - w; float a2 = a * a, a4 = a2 * a2; aC = fmaf(a4, a4, aC);
    float x = pl - w, y = pu - w;
    float dl = fmaxf(fmaxf(x, -y), 0.f);
    float e2 = dl * dl, e4 = e2 * e2; aL = fmaf(e4, e4, aL);
    float h2 = fmaxf(x * x, y * y);
    float h4 = h2 * h2; aH = fmaf(h4, h4, aH);
}

// WT[ck*O + o] = W[o*CK + ck]  (writes coalesced)
__global__ void wtrans(const float* __restrict__ W, float* __restrict__ WT, int O, int CK)
{
    int idx = blockIdx.x * blockDim.x + threadIdx.x;
    if (idx >= O * CK) return;
    int o = idx % O, ck = idx / O;
    WT[idx] = W[(size_t)o * CK + ck];
}

// conv1 (structure: wave = one o, lanes = positions).
template<int K, int S, int PAD, int CC, int HIN, int WIN, int HO, int WO>
__launch_bounds__(256)
__global__ void conv_a(const float* __restrict__ IC, const float* __restrict__ IL,
                       const float* __restrict__ IU, const float* __restrict__ W,
                       float* __restrict__ OUT, int B, int Cin, int O, int OG)
{
    constexpr int PH = (HO - 1) * S + K;
    constexpr int PW = (WO - 1) * S + K;
    constexpr int PP = PH * PW;
    constexpr int HW = HIN * WIN;
    constexpr int NP = HO * WO;
    constexpr int ROUNDS = (NP + 63) / 64;
    __shared__ float lds[CC * 3 * PP];

    int og = blockIdx.x % OG;
    int b  = (blockIdx.x / OG) % B;
    int tid = threadIdx.x;

    for (int i = tid; i < CC * 3 * PP; i += 256) lds[i] = 0.f;
    __syncthreads();
    for (int tsel = 0; tsel < 3; ++tsel) {
        const float* src = (tsel == 0 ? IC : (tsel == 1 ? IL : IU))
                         + (size_t)b * Cin * HW;
        for (int e = tid; e < CC * HW; e += 256) {
            int c = e / HW, p = e % HW;
            int pr = p / WIN, pw_ = p % WIN;
            lds[c * 3 * PP + tsel * PP + (pr + PAD) * PW + (pw_ + PAD)] = src[e];
        }
    }
    __syncthreads();

    int wave = tid >> 6, lane = tid & 63;
    int o = __builtin_amdgcn_readfirstlane(og * 4 + wave);
    const float* wp = W + (size_t)o * Cin * (K * K);

    for (int r = 0; r < ROUNDS; ++r) {
        int pos = r * 64 + lane;
        bool act = pos < NP;
        int pp = act ? pos : 0;
        int oh = pp / WO, ow = pp % WO;
        const float* sl = lds + (oh * S) * PW + ow * S;
        const float* wc = wp;
        float aC = 0.f, aL = 0.f, aH = 0.f;
        for (int c = 0; c < CC; ++c) {
            #pragma unroll
            for (int kh = 0; kh < K; ++kh)
                #pragma unroll
                for (int kw = 0; kw < K; ++kw) {
                    float w = wc[kh * K + kw];
                    tap16(w, sl[kh * PW + kw], sl[PP + kh * PW + kw],
                          sl[2 * PP + kh * PW + kw], aC, aL, aH);
                }
            sl += 3 * PP; wc += K * K;
        }
        if (act) {
            size_t N = (size_t)B * O * NP;
            size_t oidx = ((size_t)b * O + o) * NP + pos;
            OUT[oidx] = rt8(aC); OUT[N + oidx] = rt8(aL); OUT[2 * N + oidx] = rt8(aH);
        }
    }
}

// conv2: block = (chunk,b,oh), 256 threads, thread = o. Coalesced WT loads.
// Partials stored o-fastest: P[chunk*3N + tsel*N + ((b*7+oh)*7+ow)*O + o].
template<int CC>
__launch_bounds__(256)
__global__ void conv2_kernel(const float* __restrict__ IN, const float* __restrict__ WT,
                             float* __restrict__ P, int nin)
{
    constexpr int B = 16, Cin = 96, O = 256;
    constexpr size_t N = (size_t)B * O * 49;
    __shared__ float slab[CC * 165];  // c*165 + tsel*55 + r*11 + col
    int x = blockIdx.x;
    int oh   = x % 7;
    int b    = (x / 7) % B;
    int chunk = x / (7 * B);
    int c0 = chunk * CC;
    int tid = threadIdx.x;

    for (int i = tid; i < CC * 165; i += 256) {
        int c = i / 165; int rem = i - c * 165;
        int tsel = rem / 55; int rr = rem - tsel * 55;
        int r = rr / 11, col = rr - r * 11;
        int ih = oh + r - 2, iw = col - 2;
        float v = 0.f;
        if ((unsigned)ih < 7u && (unsigned)iw < 7u)
            v = IN[(size_t)tsel * nin + ((size_t)b * Cin + c0 + c) * 49 + ih * 7 + iw];
        slab[i] = v;
    }
    __syncthreads();

    int o = tid;
    float aC[7], aL[7], aH[7];
    #pragma unroll
    for (int u = 0; u < 7; ++u) { aC[u] = 0.f; aL[u] = 0.f; aH[u] = 0.f; }

    for (int c = 0; c < CC; ++c) {
        const float* wp = WT + (size_t)((c0 + c) * 25) * O + o;
        float w[25];
        #pragma unroll
        for (int t = 0; t < 25; ++t) w[t] = wp[(size_t)t * O];
        const float* sb = slab + c * 165;
        #pragma unroll
        for (int r = 0; r < 5; ++r) {
            #pragma unroll
            for (int i = 0; i < 11; ++i) {
                float xc = sb[r * 11 + i];
                float xl = sb[55 + r * 11 + i];
                float xu = sb[110 + r * 11 + i];
                #pragma unroll
                for (int ow = 0; ow < 7; ++ow) {
                    int kw = i - ow;
                    if (kw >= 0 && kw < 5)
                        tap16(w[r * 5 + kw], xc, xl, xu, aC[ow], aL[ow], aH[ow]);
                }
            }
        }
    }

    float* Pc = P + (size_t)chunk * 3 * N;
    size_t rowbase = ((size_t)(b * 7 + oh) * 7) * O + o;
    #pragma unroll
    for (int u = 0; u < 7; ++u) {
        Pc[rowbase + (size_t)u * O]         = aC[u];
        Pc[N + rowbase + (size_t)u * O]     = aL[u];
        Pc[2 * N + rowbase + (size_t)u * O] = aH[u];
    }
}

// combine conv2 partials (o-fastest layout) -> standard [b][O][7][7] layout
__global__ void conv2_combine(const float* __restrict__ P, float* __restrict__ OUT, int NCH)
{
    constexpr int B = 16, O = 256;
    constexpr size_t N = (size_t)B * O * 49;
    size_t idx = (size_t)blockIdx.x * blockDim.x + threadIdx.x;
    if (idx >= 3 * N) return;
    float s = 0.f;
    for (int ch = 0; ch < NCH; ++ch) s += P[(size_t)ch * 3 * N + idx];
    size_t tsel = idx / N; size_t r = idx % N;
    int o = (int)(r % O); int pos = (int)((r / O) % 49); int b = (int)(r / (O * 49));
    OUT[tsel * N + ((size_t)b * O + o) * 49 + pos] = rt8(s);
}

// conv3/4/5: block = (chunk,b), blockDim = O threads, thread = o.
// Partials o-fastest: P[chunk*3N + tsel*N + (b*9+pos)*O + o].
template<int CC>
__launch_bounds__(384)
__global__ void conv3x3_kernel(const float* __restrict__ IN, const float* __restrict__ WT,
                               float* __restrict__ P, int nin, int B, int Cin, int O)
{
    __shared__ float slab[CC * 75];  // c*75 + tsel*25 + iy*5 + ix
    int x = blockIdx.x;
    int b = x % B;
    int chunk = x / B;
    int c0 = chunk * CC;
    int tid = threadIdx.x;

    for (int i = tid; i < CC * 75; i += blockDim.x) {
        int c = i / 75; int rem = i - c * 75;
        int tsel = rem / 25; int rr = rem - tsel * 25;
        int iy = rr / 5, ix = rr - iy * 5;
        int ih = iy - 1, iw = ix - 1;
        float v = 0.f;
        if ((unsigned)ih < 3u && (unsigned)iw < 3u)
            v = IN[(size_t)tsel * nin + ((size_t)b * Cin + c0 + c) * 9 + ih * 3 + iw];
        slab[i] = v;
    }
    __syncthreads();

    int o = tid;
    float aC[9], aL[9], aH[9];
    #pragma unroll
    for (int u = 0; u < 9; ++u) { aC[u] = 0.f; aL[u] = 0.f; aH[u] = 0.f; }

    for (int c = 0; c < CC; ++c) {
        const float* wp = WT + (size_t)((c0 + c) * 9) * O + o;
        float w[9];
        #pragma unroll
        for (int t = 0; t < 9; ++t) w[t] = wp[(size_t)t * O];
        const float* sb = slab + c * 75;
        #pragma unroll
        for (int iy = 0; iy < 5; ++iy) {
            #pragma unroll
            for (int ix = 0; ix < 5; ++ix) {
                float xc = sb[iy * 5 + ix];
                float xl = sb[25 + iy * 5 + ix];
                float xu = sb[50 + iy * 5 + ix];
                #pragma unroll
                for (int py = 0; py < 3; ++py) {
                    int ky = iy - py;
                    if (ky < 0 || ky > 2) continue;
                    #pragma unroll
                    for (int px = 0; px < 3; ++px) {
                        int kx = ix - px;
                        if (kx < 0 || kx > 2) continue;
                        tap16(w[ky * 3 + kx], xc, xl, xu,
                              aC[py * 3 + px], aL[py * 3 + px], aH[py * 3 + px]);
                    }
                }
            }
        }
    }

    size_t N = (size_t)B * O * 9;
    float* Pc = P + (size_t)chunk * 3 * N;
    size_t base = ((size_t)b * 9) * O + o;
    #pragma unroll
    for (int u = 0; u < 9; ++u) {
        Pc[base + (size_t)u * O]         = aC[u];
        Pc[N + base + (size_t)u * O]     = aL[u];
        Pc[2 * N + base + (size_t)u * O] = aH[u];
    }
}

// combine conv3x3 partials (o-fastest) -> standard [b][O][9] layout
__global__ void conv3_combine(const float* __restrict__ P, float* __restrict__ OUT,
                              int B, int O, int NCH)
{
    size_t N = (size_t)B * O * 9;
    size_t idx = (size_t)blockIdx.x * blockDim.x + threadIdx.x;
    if (idx >= 3 * N) return;
    float s = 0.f;
    for (int ch = 0; ch < NCH; ++ch) s += P[(size_t)ch * 3 * N + idx];
    size_t tsel = idx / N; size_t r = idx % N;
    int o = (int)(r % O); int pos = (int)((r / O) % 9); int b = (int)(r / ((size_t)O * 9));
    OUT[tsel * N + ((size_t)b * O + o) * 9 + pos] = rt8(s);
}

__global__ void maxpool_kernel(const float* __restrict__ in, float* __restrict__ out,
                               int BC, int Hin, int Win, int Ho, int Wo,
                               int n_in, int n_out)
{
    int idx = blockIdx.x * blockDim.x + threadIdx.x;
    int per = BC * Ho * Wo;
    if (idx >= 3 * per) return;
    int tsel = idx / per; int r = idx - tsel * per;
    int ow = r % Wo; int t2 = r / Wo;
    int oh = t2 % Ho; int bc = t2 / Ho;
    const float* ip = in + (size_t)tsel * n_in + (size_t)bc * Hin * Win;
    int ih0 = oh * 2, iw0 = ow * 2;
    float m = -INFINITY;
    #pragma unroll
    for (int i = 0; i < 3; ++i)
        #pragma unroll
        for (int j = 0; j < 3; ++j)
            m = fmaxf(m, ip[(ih0 + i) * Win + (iw0 + j)]);
    out[(size_t)tsel * n_out + r] = m;
}

// FC partial with transposed weights: thread (chunk,b,o); w coalesced over o,
// inputs wave-uniform scalar loads.
__global__ void fc_partial_t(
    const float* __restrict__ IC, const float* __restrict__ IL, const float* __restrict__ IU,
    const float* __restrict__ WT, float* __restrict__ P,
    int B, int In, int Out, int CC, int NCH)
{
    int idx = blockIdx.x * blockDim.x + threadIdx.x;
    if (idx >= NCH * B * Out) return;
    int o = idx % Out; int t = idx / Out;
    int b = t % B; int chunk = t / B;
    int i0 = chunk * CC;
    const float* cr = IC + (size_t)b * In + i0;
    const float* lr = IL + (size_t)b * In + i0;
    const float* ur = IU + (size_t)b * In + i0;
    const float* wp = WT + (size_t)i0 * Out + o;
    float sc = 0.f, sm = 0.f, sr = 0.f;
    for (int i = 0; i < CC; ++i) {
        float w = wp[(size_t)i * Out];
        float c = cr[i], l = lr[i], u = ur[i];
        sc = fmaf(c, w, sc);
        sm = fmaf((l + u) * 0.5f, w, sm);
        sr = fmaf((u - l) * 0.5f, fabsf(w), sr);
    }
    size_t N = (size_t)B * Out;
    size_t base = (size_t)b * Out + o;
    float* p = P + (size_t)chunk * 3 * N;
    p[base] = sc; p[N + base] = sm; p[2 * N + base] = sr;
}

__global__ void fc_combine(const float* __restrict__ P, float* __restrict__ OUT,
                           size_t N, int NCH)
{
    size_t idx = (size_t)blockIdx.x * blockDim.x + threadIdx.x;
    if (idx >= N) return;
    float sc = 0.f, sm = 0.f, sr = 0.f;
    for (int ch = 0; ch < NCH; ++ch) {
        const float* p = P + (size_t)ch * 3 * N;
        sc += p[idx]; sm += p[N + idx]; sr += p[2 * N + idx];
    }
    OUT[idx]         = fmaxf(sc, 0.f);
    OUT[N + idx]     = fmaxf(sm - sr, 0.f);
    OUT[2 * N + idx] = fmaxf(sm + sr, 0.f);
}

__global__ void bound_linear_kernel(
    const float* __restrict__ IC, const float* __restrict__ IL, const float* __restrict__ IU,
    const float* __restrict__ W, const float* __restrict__ bias,
    float* __restrict__ OC, float* __restrict__ OL, float* __restrict__ OU,
    int B, int In, int Out)
{
    int idx = blockIdx.x * blockDim.x + threadIdx.x;
    if (idx >= B * Out) return;
    int o = idx % Out, b = idx / Out;
    const float* wr = W  + (size_t)o * In;
    const float* cr = IC + (size_t)b * In;
    const float* lr = IL + (size_t)b * In;
    const float* ur = IU + (size_t)b * In;
    float sc = 0.f, sm = 0.f, sr = 0.f;
    for (int i = 0; i < In; ++i) {
        float w = wr[i];
        sc = fmaf(cr[i], w, sc);
        sm = fmaf((lr[i] + ur[i]) * 0.5f, w, sm);
        sr = fmaf((ur[i] - lr[i]) * 0.5f, fabsf(w), sr);
    }
    float bb = bias[o]; sc += bb; sm += bb;
    OC[idx] = -sc; OL[idx] = -(sm - sr); OU[idx] = -(sm + sr);
}

extern "C" void kernel_launch(void* const* d_in, const int* in_sizes, int n_in,
                              void* d_out, int out_size, void* d_ws, size_t ws_size,
                              hipStream_t stream)
{
    const float* x   = (const float*)d_in[0];
    const float* lo  = (const float*)d_in[1];
    const float* hi  = (const float*)d_in[2];
    const float* w1  = (const float*)d_in[3];
    const float* w2  = (const float*)d_in[4];
    const float* w3  = (const float*)d_in[5];
    const float* w4  = (const float*)d_in[6];
    const float* w5  = (const float*)d_in[7];
    const float* fw1 = (const float*)d_in[8];
    const float* fw2 = (const float*)d_in[9];
    const float* fw3 = (const float*)d_in[10];
    const float* fb3 = (const float*)d_in[11];
    float* out = (float*)d_out;
    float* ws  = (float*)d_ws;

    const size_t n_c1 = 16u * 96 * 15 * 15;
    const size_t n_p1 = 16u * 96 * 7 * 7;
    const size_t n_c2 = 16u * 256 * 7 * 7;
    const size_t n_p2 = 16u * 256 * 3 * 3;
    const size_t n_c3 = 16u * 384 * 3 * 3;
    const size_t n_c4 = n_c3;
    const size_t n_c5 = 16u * 256 * 3 * 3;
    const size_t n_f1 = 16u * 1024;
    const size_t n_f2 = 16u * 512;

    float* A   = ws;
    float* Bp  = A  + 3 * n_c1;
    float* Cc  = Bp + 3 * n_p1;
    float* D   = Cc + 3 * n_c2;
    float* E   = D  + 3 * n_p2;
    float* F   = E  + 3 * n_c3;
    float* G   = F  + 3 * n_c4;
    float* H   = G  + 3 * n_c5;
    float* I   = H  + 3 * n_f1;
    float* SP  = I  + 3 * n_f2;          // partial scratch, 8.0M floats
    float* WT2 = SP + 8000000;           // 614400
    float* WT3 = WT2 + 614400;           // 884736
    float* WT4 = WT3 + 884736;           // 1327104
    float* WT5 = WT4 + 1327104;          // 884736
    // fc weight transposes live inside SP (conv partials dead by then)
    float* WTF1 = SP + 1000000;          // 2359296
    float* WTF2 = SP + 3500000;          // 524288

    const int BS = 256;
    auto grid = [](size_t tot) { return dim3((unsigned)((tot + 255) / 256)); };

    // conv weight transposes
    wtrans<<<grid(614400),  BS, 0, stream>>>(w2, WT2, 256, 2400);
    wtrans<<<grid(884736),  BS, 0, stream>>>(w3, WT3, 384, 2304);
    wtrans<<<grid(1327104), BS, 0, stream>>>(w4, WT4, 384, 3456);
    wtrans<<<grid(884736),  BS, 0, stream>>>(w5, WT5, 256, 3456);

    // conv1: [16,3,32,32] k7 s2 p2 -> [16,96,15,15]
    conv_a<7, 2, 2, 3, 32, 32, 15, 15><<<384, BS, 0, stream>>>(
        x, lo, hi, w1, A, 16, 3, 96, 24);
    // pool1
    maxpool_kernel<<<grid(3 * n_p1), BS, 0, stream>>>(
        A, Bp, 16 * 96, 15, 15, 7, 7, (int)n_c1, (int)n_p1);
    // conv2: NCH=12, CC=8; grid = 12*16*7 blocks of 256
    conv2_kernel<8><<<12 * 16 * 7, 256, 0, stream>>>(Bp, WT2, SP, (int)n_p1);
    conv2_combine<<<grid(3 * n_c2), BS, 0, stream>>>(SP, Cc, 12);
    // pool2
    maxpool_kernel<<<grid(3 * n_p2), BS, 0, stream>>>(
        Cc, D, 16 * 256, 7, 7, 3, 3, (int)n_c2, (int)n_p2);
    // conv3: Cin=256 O=384; NCH=32, CC=8; 512 blocks of 384
    conv3x3_kernel<8><<<32 * 16, 384, 0, stream>>>(
        D, WT3, SP, (int)n_p2, 16, 256, 384);
    conv3_combine<<<grid(3 * n_c3), BS, 0, stream>>>(SP, E, 16, 384, 32);
    // conv4: Cin=384 O=384; NCH=48, CC=8; 768 blocks of 384
    conv3x3_kernel<8><<<48 * 16, 384, 0, stream>>>(
        E, WT4, SP, (int)n_c3, 16, 384, 384);
    conv3_combine<<<grid(3 * n_c4), BS, 0, stream>>>(SP, F, 16, 384, 48);
    // conv5: Cin=384 O=256; NCH=48, CC=8; 768 blocks of 256
    conv3x3_kernel<8><<<48 * 16, 256, 0, stream>>>(
        F, WT5, SP, (int)n_c4, 16, 384, 256);
    conv3_combine<<<grid(3 * n_c5), BS, 0, stream>>>(SP, G, 16, 256, 48);
    // fc weight transposes (SP conv partials now dead)
    wtrans<<<grid(2359296), BS, 0, stream>>>(fw1, WTF1, 1024, 2304);
    wtrans<<<grid(524288),  BS, 0, stream>>>(fw2, WTF2, 512, 1024);
    // fc1: 2304 -> 1024, relu; split 8x288
    fc_partial_t<<<grid(8u * 16 * 1024), BS, 0, stream>>>(
        G, G + n_c5, G + 2 * n_c5, WTF1, SP, 16, 2304, 1024, 288, 8);
    fc_combine<<<grid(n_f1), BS, 0, stream>>>(SP, H, n_f1, 8);
    // fc2: 1024 -> 512, relu; split 8x128
    fc_partial_t<<<grid(8u * 16 * 512), BS, 0, stream>>>(
        H, H + n_f1, H + 2 * n_f1, WTF2, SP, 16, 1024, 512, 128, 8);
    fc_combine<<<grid(n_f2), BS, 0, stream>>>(SP, I, n_f2, 8);
    // fc3: 512 -> 10, +bias, negate+swap: out = [-c | -u | -l]
    bound_linear_kernel<<<grid(160), BS, 0, stream>>>(
        I, I + n_f2, I + 2 * n_f2, fw3, fb3,
        out, out + 320, out + 160, 16, 512, 10);
}

// Round 6
// 670.143 us; speedup vs baseline: 1.2092x; 1.2092x over previous
//
#include <hip/hip_runtime.h>
#include <math.h>

// ---------------------------------------------------------------------------
// NormDist (Lp, p=8) IBP AlexNet. Round 6: batched LDS-tiled weight transpose
// (one kernel, coalesced both sides), wave-per-output GEMV for fc1/fc2 (no
// transpose needed), conv2 with more channel chunks for latency hiding.
// lp8(d) = (sum d^8)^(1/8); relu after conv = no-op (norms >= 0).
// ---------------------------------------------------------------------------

__device__ __forceinline__ float rt8(float s) { return sqrtf(sqrtf(sqrtf(s))); }

__device__ __forceinline__ void tap16(float w, float pc, float pl, float pu,
                                      float& aC, float& aL, float& aH)
{
    float a = pc - w; float a2 = a * a, a4 = a2 * a2; aC = fmaf(a4, a4, aC);
    float x = pl - w, y = pu - w;
    float dl = fmaxf(fmaxf(x, -y), 0.f);
    float e2 = dl * dl, e4 = e2 * e2; aL = fmaf(e4, e4, aL);
    float h2 = fmaxf(x * x, y * y);
    float h4 = h2 * h2; aH = fmaf(h4, h4, aH);
}

// Batched 64x64 LDS-tiled transpose of w2..w5 (O always % 64 == 0).
__launch_bounds__(256)
__global__ void wtrans4(const float* __restrict__ W2, const float* __restrict__ W3,
                        const float* __restrict__ W4, const float* __restrict__ W5,
                        float* __restrict__ T2, float* __restrict__ T3,
                        float* __restrict__ T4, float* __restrict__ T5)
{
    constexpr int nt2 = 4 * 38, nt3 = 6 * 36, nt4 = 6 * 54, nt5 = 4 * 54;
    int bid = blockIdx.x;
    const float* W; float* T; int O, CK, t;
    if (bid < nt2)                   { W = W2; T = T2; O = 256; CK = 2400; t = bid; }
    else if (bid < nt2 + nt3)        { W = W3; T = T3; O = 384; CK = 2304; t = bid - nt2; }
    else if (bid < nt2 + nt3 + nt4)  { W = W4; T = T4; O = 384; CK = 3456; t = bid - nt2 - nt3; }
    else                             { W = W5; T = T5; O = 256; CK = 3456; t = bid - nt2 - nt3 - nt4; }
    int tilesC = (CK + 63) / 64;
    int to = t / tilesC, tc = t - to * tilesC;
    int o0 = to * 64, c0 = tc * 64;
    __shared__ float tile[64][65];
    int lane = threadIdx.x & 63, wv = threadIdx.x >> 6;
    #pragma unroll
    for (int i = 0; i < 16; ++i) {
        int row = wv + i * 4;
        int c = c0 + lane;
        tile[row][lane] = (c < CK) ? W[(size_t)(o0 + row) * CK + c] : 0.f;
    }
    __syncthreads();
    #pragma unroll
    for (int i = 0; i < 16; ++i) {
        int row = wv + i * 4;
        int c = c0 + row;
        if (c < CK) T[(size_t)c * O + o0 + lane] = tile[lane][row];
    }
}

// conv1 (wave = one o, lanes = positions).
template<int K, int S, int PAD, int CC, int HIN, int WIN, int HO, int WO>
__launch_bounds__(256)
__global__ void conv_a(const float* __restrict__ IC, const float* __restrict__ IL,
                       const float* __restrict__ IU, const float* __restrict__ W,
                       float* __restrict__ OUT, int B, int Cin, int O, int OG)
{
    constexpr int PH = (HO - 1) * S + K;
    constexpr int PW = (WO - 1) * S + K;
    constexpr int PP = PH * PW;
    constexpr int HW = HIN * WIN;
    constexpr int NP = HO * WO;
    constexpr int ROUNDS = (NP + 63) / 64;
    __shared__ float lds[CC * 3 * PP];

    int og = blockIdx.x % OG;
    int b  = (blockIdx.x / OG) % B;
    int tid = threadIdx.x;

    for (int i = tid; i < CC * 3 * PP; i += 256) lds[i] = 0.f;
    __syncthreads();
    for (int tsel = 0; tsel < 3; ++tsel) {
        const float* src = (tsel == 0 ? IC : (tsel == 1 ? IL : IU))
                         + (size_t)b * Cin * HW;
        for (int e = tid; e < CC * HW; e += 256) {
            int c = e / HW, p = e % HW;
            int pr = p / WIN, pw_ = p % WIN;
            lds[c * 3 * PP + tsel * PP + (pr + PAD) * PW + (pw_ + PAD)] = src[e];
        }
    }
    __syncthreads();

    int wave = tid >> 6, lane = tid & 63;
    int o = __builtin_amdgcn_readfirstlane(og * 4 + wave);
    const float* wp = W + (size_t)o * Cin * (K * K);

    for (int r = 0; r < ROUNDS; ++r) {
        int pos = r * 64 + lane;
        bool act = pos < NP;
        int pp = act ? pos : 0;
        int oh = pp / WO, ow = pp % WO;
        const float* sl = lds + (oh * S) * PW + ow * S;
        const float* wc = wp;
        float aC = 0.f, aL = 0.f, aH = 0.f;
        for (int c = 0; c < CC; ++c) {
            #pragma unroll
            for (int kh = 0; kh < K; ++kh)
                #pragma unroll
                for (int kw = 0; kw < K; ++kw) {
                    float w = wc[kh * K + kw];
                    tap16(w, sl[kh * PW + kw], sl[PP + kh * PW + kw],
                          sl[2 * PP + kh * PW + kw], aC, aL, aH);
                }
            sl += 3 * PP; wc += K * K;
        }
        if (act) {
            size_t N = (size_t)B * O * NP;
            size_t oidx = ((size_t)b * O + o) * NP + pos;
            OUT[oidx] = rt8(aC); OUT[N + oidx] = rt8(aL); OUT[2 * N + oidx] = rt8(aH);
        }
    }
}

// conv2: block = (chunk,b,oh), 256 threads, thread = o. Coalesced WT loads.
template<int CC>
__launch_bounds__(256)
__global__ void conv2_kernel(const float* __restrict__ IN, const float* __restrict__ WT,
                             float* __restrict__ P, int nin)
{
    constexpr int B = 16, Cin = 96, O = 256;
    constexpr size_t N = (size_t)B * O * 49;
    __shared__ float slab[CC * 165];  // c*165 + tsel*55 + r*11 + col
    int x = blockIdx.x;
    int oh   = x % 7;
    int b    = (x / 7) % B;
    int chunk = x / (7 * B);
    int c0 = chunk * CC;
    int tid = threadIdx.x;

    for (int i = tid; i < CC * 165; i += 256) {
        int c = i / 165; int rem = i - c * 165;
        int tsel = rem / 55; int rr = rem - tsel * 55;
        int r = rr / 11, col = rr - r * 11;
        int ih = oh + r - 2, iw = col - 2;
        float v = 0.f;
        if ((unsigned)ih < 7u && (unsigned)iw < 7u)
            v = IN[(size_t)tsel * nin + ((size_t)b * Cin + c0 + c) * 49 + ih * 7 + iw];
        slab[i] = v;
    }
    __syncthreads();

    int o = tid;
    float aC[7], aL[7], aH[7];
    #pragma unroll
    for (int u = 0; u < 7; ++u) { aC[u] = 0.f; aL[u] = 0.f; aH[u] = 0.f; }

    for (int c = 0; c < CC; ++c) {
        const float* wp = WT + (size_t)((c0 + c) * 25) * O + o;
        float w[25];
        #pragma unroll
        for (int t = 0; t < 25; ++t) w[t] = wp[(size_t)t * O];
        const float* sb = slab + c * 165;
        #pragma unroll
        for (int r = 0; r < 5; ++r) {
            #pragma unroll
            for (int i = 0; i < 11; ++i) {
                float xc = sb[r * 11 + i];
                float xl = sb[55 + r * 11 + i];
                float xu = sb[110 + r * 11 + i];
                #pragma unroll
                for (int ow = 0; ow < 7; ++ow) {
                    int kw = i - ow;
                    if (kw >= 0 && kw < 5)
                        tap16(w[r * 5 + kw], xc, xl, xu, aC[ow], aL[ow], aH[ow]);
                }
            }
        }
    }

    float* Pc = P + (size_t)chunk * 3 * N;
    size_t rowbase = ((size_t)(b * 7 + oh) * 7) * O + o;
    #pragma unroll
    for (int u = 0; u < 7; ++u) {
        Pc[rowbase + (size_t)u * O]         = aC[u];
        Pc[N + rowbase + (size_t)u * O]     = aL[u];
        Pc[2 * N + rowbase + (size_t)u * O] = aH[u];
    }
}

// combine conv2 partials (o-fastest layout) -> standard [b][O][7][7] layout
__global__ void conv2_combine(const float* __restrict__ P, float* __restrict__ OUT, int NCH)
{
    constexpr int B = 16, O = 256;
    constexpr size_t N = (size_t)B * O * 49;
    size_t idx = (size_t)blockIdx.x * blockDim.x + threadIdx.x;
    if (idx >= 3 * N) return;
    float s = 0.f;
    for (int ch = 0; ch < NCH; ++ch) s += P[(size_t)ch * 3 * N + idx];
    size_t tsel = idx / N; size_t r = idx % N;
    int o = (int)(r % O); int pos = (int)((r / O) % 49); int b = (int)(r / (O * 49));
    OUT[tsel * N + ((size_t)b * O + o) * 49 + pos] = rt8(s);
}

// conv3/4/5: block = (chunk,b), blockDim = O threads, thread = o.
template<int CC>
__launch_bounds__(384)
__global__ void conv3x3_kernel(const float* __restrict__ IN, const float* __restrict__ WT,
                               float* __restrict__ P, int nin, int B, int Cin, int O)
{
    __shared__ float slab[CC * 75];  // c*75 + tsel*25 + iy*5 + ix
    int x = blockIdx.x;
    int b = x % B;
    int chunk = x / B;
    int c0 = chunk * CC;
    int tid = threadIdx.x;

    for (int i = tid; i < CC * 75; i += blockDim.x) {
        int c = i / 75; int rem = i - c * 75;
        int tsel = rem / 25; int rr = rem - tsel * 25;
        int iy = rr / 5, ix = rr - iy * 5;
        int ih = iy - 1, iw = ix - 1;
        float v = 0.f;
        if ((unsigned)ih < 3u && (unsigned)iw < 3u)
            v = IN[(size_t)tsel * nin + ((size_t)b * Cin + c0 + c) * 9 + ih * 3 + iw];
        slab[i] = v;
    }
    __syncthreads();

    int o = tid;
    float aC[9], aL[9], aH[9];
    #pragma unroll
    for (int u = 0; u < 9; ++u) { aC[u] = 0.f; aL[u] = 0.f; aH[u] = 0.f; }

    for (int c = 0; c < CC; ++c) {
        const float* wp = WT + (size_t)((c0 + c) * 9) * O + o;
        float w[9];
        #pragma unroll
        for (int t = 0; t < 9; ++t) w[t] = wp[(size_t)t * O];
        const float* sb = slab + c * 75;
        #pragma unroll
        for (int iy = 0; iy < 5; ++iy) {
            #pragma unroll
            for (int ix = 0; ix < 5; ++ix) {
                float xc = sb[iy * 5 + ix];
                float xl = sb[25 + iy * 5 + ix];
                float xu = sb[50 + iy * 5 + ix];
                #pragma unroll
                for (int py = 0; py < 3; ++py) {
                    int ky = iy - py;
                    if (ky < 0 || ky > 2) continue;
                    #pragma unroll
                    for (int px = 0; px < 3; ++px) {
                        int kx = ix - px;
                        if (kx < 0 || kx > 2) continue;
                        tap16(w[ky * 3 + kx], xc, xl, xu,
                              aC[py * 3 + px], aL[py * 3 + px], aH[py * 3 + px]);
                    }
                }
            }
        }
    }

    size_t N = (size_t)B * O * 9;
    float* Pc = P + (size_t)chunk * 3 * N;
    size_t base = ((size_t)b * 9) * O + o;
    #pragma unroll
    for (int u = 0; u < 9; ++u) {
        Pc[base + (size_t)u * O]         = aC[u];
        Pc[N + base + (size_t)u * O]     = aL[u];
        Pc[2 * N + base + (size_t)u * O] = aH[u];
    }
}

// combine conv3x3 partials (o-fastest) -> standard [b][O][9] layout
__global__ void conv3_combine(const float* __restrict__ P, float* __restrict__ OUT,
                              int B, int O, int NCH)
{
    size_t N = (size_t)B * O * 9;
    size_t idx = (size_t)blockIdx.x * blockDim.x + threadIdx.x;
    if (idx >= 3 * N) return;
    float s = 0.f;
    for (int ch = 0; ch < NCH; ++ch) s += P[(size_t)ch * 3 * N + idx];
    size_t tsel = idx / N; size_t r = idx % N;
    int o = (int)(r % O); int pos = (int)((r / O) % 9); int b = (int)(r / ((size_t)O * 9));
    OUT[tsel * N + ((size_t)b * O + o) * 9 + pos] = rt8(s);
}

__global__ void maxpool_kernel(const float* __restrict__ in, float* __restrict__ out,
                               int BC, int Hin, int Win, int Ho, int Wo,
                               int n_in, int n_out)
{
    int idx = blockIdx.x * blockDim.x + threadIdx.x;
    int per = BC * Ho * Wo;
    if (idx >= 3 * per) return;
    int tsel = idx / per; int r = idx - tsel * per;
    int ow = r % Wo; int t2 = r / Wo;
    int oh = t2 % Ho; int bc = t2 / Ho;
    const float* ip = in + (size_t)tsel * n_in + (size_t)bc * Hin * Win;
    int ih0 = oh * 2, iw0 = ow * 2;
    float m = -INFINITY;
    #pragma unroll
    for (int i = 0; i < 3; ++i)
        #pragma unroll
        for (int j = 0; j < 3; ++j)
            m = fmaxf(m, ip[(ih0 + i) * Win + (iw0 + j)]);
    out[(size_t)tsel * n_out + r] = m;
}

// fc1/fc2: wave per (b,o); float4 coalesced loads of untransposed row; butterfly
// reduce; relu epilogue. Writes c/l/h at OUT,+N,+2N.
__launch_bounds__(256)
__global__ void fc_gemv(const float* __restrict__ IC, const float* __restrict__ IL,
                        const float* __restrict__ IU, const float* __restrict__ W,
                        float* __restrict__ OUT, int B, int In, int Out)
{
    int gw = (int)((blockIdx.x * blockDim.x + threadIdx.x) >> 6);
    int lane = threadIdx.x & 63;
    if (gw >= B * Out) return;
    int o = gw % Out, b = gw / Out;
    const float4* wr = (const float4*)(W  + (size_t)o * In);
    const float4* cr = (const float4*)(IC + (size_t)b * In);
    const float4* lr = (const float4*)(IL + (size_t)b * In);
    const float4* ur = (const float4*)(IU + (size_t)b * In);
    int In4 = In >> 2;
    float sc = 0.f, sm = 0.f, sr = 0.f;
    for (int i = lane; i < In4; i += 64) {
        float4 w4 = wr[i], c4 = cr[i], l4 = lr[i], u4 = ur[i];
        sc = fmaf(c4.x, w4.x, sc); sc = fmaf(c4.y, w4.y, sc);
        sc = fmaf(c4.z, w4.z, sc); sc = fmaf(c4.w, w4.w, sc);
        sm = fmaf((l4.x + u4.x) * 0.5f, w4.x, sm);
        sm = fmaf((l4.y + u4.y) * 0.5f, w4.y, sm);
        sm = fmaf((l4.z + u4.z) * 0.5f, w4.z, sm);
        sm = fmaf((l4.w + u4.w) * 0.5f, w4.w, sm);
        sr = fmaf((u4.x - l4.x) * 0.5f, fabsf(w4.x), sr);
        sr = fmaf((u4.y - l4.y) * 0.5f, fabsf(w4.y), sr);
        sr = fmaf((u4.z - l4.z) * 0.5f, fabsf(w4.z), sr);
        sr = fmaf((u4.w - l4.w) * 0.5f, fabsf(w4.w), sr);
    }
    #pragma unroll
    for (int off = 32; off; off >>= 1) {
        sc += __shfl_xor(sc, off);
        sm += __shfl_xor(sm, off);
        sr += __shfl_xor(sr, off);
    }
    if (lane == 0) {
        size_t N = (size_t)B * Out;
        size_t idx = (size_t)b * Out + o;
        OUT[idx]         = fmaxf(sc, 0.f);
        OUT[N + idx]     = fmaxf(sm - sr, 0.f);
        OUT[2 * N + idx] = fmaxf(sm + sr, 0.f);
    }
}

__global__ void bound_linear_kernel(
    const float* __restrict__ IC, const float* __restrict__ IL, const float* __restrict__ IU,
    const float* __restrict__ W, const float* __restrict__ bias,
    float* __restrict__ OC, float* __restrict__ OL, float* __restrict__ OU,
    int B, int In, int Out)
{
    int idx = blockIdx.x * blockDim.x + threadIdx.x;
    if (idx >= B * Out) return;
    int o = idx % Out, b = idx / Out;
    const float* wr = W  + (size_t)o * In;
    const float* cr = IC + (size_t)b * In;
    const float* lr = IL + (size_t)b * In;
    const float* ur = IU + (size_t)b * In;
    float sc = 0.f, sm = 0.f, sr = 0.f;
    for (int i = 0; i < In; ++i) {
        float w = wr[i];
        sc = fmaf(cr[i], w, sc);
        sm = fmaf((lr[i] + ur[i]) * 0.5f, w, sm);
        sr = fmaf((ur[i] - lr[i]) * 0.5f, fabsf(w), sr);
    }
    float bb = bias[o]; sc += bb; sm += bb;
    OC[idx] = -sc; OL[idx] = -(sm - sr); OU[idx] = -(sm + sr);
}

extern "C" void kernel_launch(void* const* d_in, const int* in_sizes, int n_in,
                              void* d_out, int out_size, void* d_ws, size_t ws_size,
                              hipStream_t stream)
{
    const float* x   = (const float*)d_in[0];
    const float* lo  = (const float*)d_in[1];
    const float* hi  = (const float*)d_in[2];
    const float* w1  = (const float*)d_in[3];
    const float* w2  = (const float*)d_in[4];
    const float* w3  = (const float*)d_in[5];
    const float* w4  = (const float*)d_in[6];
    const float* w5  = (const float*)d_in[7];
    const float* fw1 = (const float*)d_in[8];
    const float* fw2 = (const float*)d_in[9];
    const float* fw3 = (const float*)d_in[10];
    const float* fb3 = (const float*)d_in[11];
    float* out = (float*)d_out;
    float* ws  = (float*)d_ws;

    const size_t n_c1 = 16u * 96 * 15 * 15;
    const size_t n_p1 = 16u * 96 * 7 * 7;
    const size_t n_c2 = 16u * 256 * 7 * 7;
    const size_t n_p2 = 16u * 256 * 3 * 3;
    const size_t n_c3 = 16u * 384 * 3 * 3;
    const size_t n_c4 = n_c3;
    const size_t n_c5 = 16u * 256 * 3 * 3;
    const size_t n_f1 = 16u * 1024;
    const size_t n_f2 = 16u * 512;

    float* A   = ws;
    float* Bp  = A  + 3 * n_c1;
    float* Cc  = Bp + 3 * n_p1;
    float* D   = Cc + 3 * n_c2;
    float* E   = D  + 3 * n_p2;
    float* F   = E  + 3 * n_c3;
    float* G   = F  + 3 * n_c4;
    float* H   = G  + 3 * n_c5;
    float* I   = H  + 3 * n_f1;
    float* WT2 = I  + 3 * n_f2;          // 614400
    float* WT3 = WT2 + 614400;           // 884736
    float* WT4 = WT3 + 884736;           // 1327104
    float* WT5 = WT4 + 1327104;          // 884736
    float* SP  = WT5 + 884736;           // partial scratch: max 16*3*n_c2 = 9.63M floats

    const int BS = 256;
    auto grid = [](size_t tot) { return dim3((unsigned)((tot + 255) / 256)); };

    // batched conv weight transposes (one kernel, LDS-tiled)
    wtrans4<<<4 * 38 + 6 * 36 + 6 * 54 + 4 * 54, BS, 0, stream>>>(
        w2, w3, w4, w5, WT2, WT3, WT4, WT5);

    // conv1: [16,3,32,32] k7 s2 p2 -> [16,96,15,15]
    conv_a<7, 2, 2, 3, 32, 32, 15, 15><<<384, BS, 0, stream>>>(
        x, lo, hi, w1, A, 16, 3, 96, 24);
    // pool1
    maxpool_kernel<<<grid(3 * n_p1), BS, 0, stream>>>(
        A, Bp, 16 * 96, 15, 15, 7, 7, (int)n_c1, (int)n_p1);
    // conv2: NCH=16, CC=6; grid = 16*16*7 = 1792 blocks of 256
    conv2_kernel<6><<<16 * 16 * 7, 256, 0, stream>>>(Bp, WT2, SP, (int)n_p1);
    conv2_combine<<<grid(3 * n_c2), BS, 0, stream>>>(SP, Cc, 16);
    // pool2
    maxpool_kernel<<<grid(3 * n_p2), BS, 0, stream>>>(
        Cc, D, 16 * 256, 7, 7, 3, 3, (int)n_c2, (int)n_p2);
    // conv3: Cin=256 O=384; NCH=32, CC=8; 512 blocks of 384
    conv3x3_kernel<8><<<32 * 16, 384, 0, stream>>>(
        D, WT3, SP, (int)n_p2, 16, 256, 384);
    conv3_combine<<<grid(3 * n_c3), BS, 0, stream>>>(SP, E, 16, 384, 32);
    // conv4: Cin=384 O=384; NCH=48, CC=8; 768 blocks of 384
    conv3x3_kernel<8><<<48 * 16, 384, 0, stream>>>(
        E, WT4, SP, (int)n_c3, 16, 384, 384);
    conv3_combine<<<grid(3 * n_c4), BS, 0, stream>>>(SP, F, 16, 384, 48);
    // conv5: Cin=384 O=256; NCH=48, CC=8; 768 blocks of 256
    conv3x3_kernel<8><<<48 * 16, 256, 0, stream>>>(
        F, WT5, SP, (int)n_c4, 16, 384, 256);
    conv3_combine<<<grid(3 * n_c5), BS, 0, stream>>>(SP, G, 16, 256, 48);
    // fc1: 2304 -> 1024, relu; wave per (b,o): 16384 waves
    fc_gemv<<<grid(16384u * 64), BS, 0, stream>>>(
        G, G + n_c5, G + 2 * n_c5, fw1, H, 16, 2304, 1024);
    // fc2: 1024 -> 512, relu; 8192 waves
    fc_gemv<<<grid(8192u * 64), BS, 0, stream>>>(
        H, H + n_f1, H + 2 * n_f1, fw2, I, 16, 1024, 512);
    // fc3: 512 -> 10, +bias, negate+swap: out = [-c | -u | -l]
    bound_linear_kernel<<<grid(160), BS, 0, stream>>>(
        I, I + n_f2, I + 2 * n_f2, fw3, fb3,
        out, out + 320, out + 160, 16, 512, 10);
}

// Round 7
// 655.026 us; speedup vs baseline: 1.2371x; 1.0231x over previous
//
#include <hip/hip_runtime.h>
#include <math.h>

// ---------------------------------------------------------------------------
// NormDist (Lp, p=8) IBP AlexNet. Round 7:
//  - conv2: LDS rows padded to 12 floats -> ds_read_b128 row loads; inner loop
//    explicit ow*kw unroll (constant indices only).
//  - rt8 fused through maxpool (monotonic): conv1 writes raw sums, pool1 does
//    rt8; conv2-combine + pool2 fused into one kernel.
//  - pos-major [tsel][b][pos][C] intermediates (D,E,F): combines are pure
//    coalesced sum+rt8; conv3/4/5 staging reads contiguous channels.
// lp8(d) = (sum d^8)^(1/8); relu after conv = no-op (norms >= 0).
// ---------------------------------------------------------------------------

__device__ __forceinline__ float rt8(float s) { return sqrtf(sqrtf(sqrtf(s))); }

__device__ __forceinline__ void tap16(float w, float pc, float pl, float pu,
                                      float& aC, float& aL, float& aH)
{
    float a = pc - w; float a2 = a * a, a4 = a2 * a2; aC = fmaf(a4, a4, aC);
    float x = pl - w, y = pu - w;
    float dl = fmaxf(fmaxf(x, -y), 0.f);
    float e2 = dl * dl, e4 = e2 * e2; aL = fmaf(e4, e4, aL);
    float h2 = fmaxf(x * x, y * y);
    float h4 = h2 * h2; aH = fmaf(h4, h4, aH);
}

// Batched 64x64 LDS-tiled transpose of w2..w5.
__launch_bounds__(256)
__global__ void wtrans4(const float* __restrict__ W2, const float* __restrict__ W3,
                        const float* __restrict__ W4, const float* __restrict__ W5,
                        float* __restrict__ T2, float* __restrict__ T3,
                        float* __restrict__ T4, float* __restrict__ T5)
{
    constexpr int nt2 = 4 * 38, nt3 = 6 * 36, nt4 = 6 * 54, nt5 = 4 * 54;
    int bid = blockIdx.x;
    const float* W; float* T; int O, CK, t;
    if (bid < nt2)                   { W = W2; T = T2; O = 256; CK = 2400; t = bid; }
    else if (bid < nt2 + nt3)        { W = W3; T = T3; O = 384; CK = 2304; t = bid - nt2; }
    else if (bid < nt2 + nt3 + nt4)  { W = W4; T = T4; O = 384; CK = 3456; t = bid - nt2 - nt3; }
    else                             { W = W5; T = T5; O = 256; CK = 3456; t = bid - nt2 - nt3 - nt4; }
    int tilesC = (CK + 63) / 64;
    int to = t / tilesC, tc = t - to * tilesC;
    int o0 = to * 64, c0 = tc * 64;
    __shared__ float tile[64][65];
    int lane = threadIdx.x & 63, wv = threadIdx.x >> 6;
    #pragma unroll
    for (int i = 0; i < 16; ++i) {
        int row = wv + i * 4;
        int c = c0 + lane;
        tile[row][lane] = (c < CK) ? W[(size_t)(o0 + row) * CK + c] : 0.f;
    }
    __syncthreads();
    #pragma unroll
    for (int i = 0; i < 16; ++i) {
        int row = wv + i * 4;
        int c = c0 + row;
        if (c < CK) T[(size_t)c * O + o0 + lane] = tile[lane][row];
    }
}

// conv1 (wave = one o, lanes = positions). Writes RAW d^8 sums (rt8 in pool1).
template<int K, int S, int PAD, int CC, int HIN, int WIN, int HO, int WO>
__launch_bounds__(256)
__global__ void conv_a(const float* __restrict__ IC, const float* __restrict__ IL,
                       const float* __restrict__ IU, const float* __restrict__ W,
                       float* __restrict__ OUT, int B, int Cin, int O, int OG)
{
    constexpr int PH = (HO - 1) * S + K;
    constexpr int PW = (WO - 1) * S + K;
    constexpr int PP = PH * PW;
    constexpr int HW = HIN * WIN;
    constexpr int NP = HO * WO;
    constexpr int ROUNDS = (NP + 63) / 64;
    __shared__ float lds[CC * 3 * PP];

    int og = blockIdx.x % OG;
    int b  = (blockIdx.x / OG) % B;
    int tid = threadIdx.x;

    for (int i = tid; i < CC * 3 * PP; i += 256) lds[i] = 0.f;
    __syncthreads();
    for (int tsel = 0; tsel < 3; ++tsel) {
        const float* src = (tsel == 0 ? IC : (tsel == 1 ? IL : IU))
                         + (size_t)b * Cin * HW;
        for (int e = tid; e < CC * HW; e += 256) {
            int c = e / HW, p = e % HW;
            int pr = p / WIN, pw_ = p % WIN;
            lds[c * 3 * PP + tsel * PP + (pr + PAD) * PW + (pw_ + PAD)] = src[e];
        }
    }
    __syncthreads();

    int wave = tid >> 6, lane = tid & 63;
    int o = __builtin_amdgcn_readfirstlane(og * 4 + wave);
    const float* wp = W + (size_t)o * Cin * (K * K);

    for (int r = 0; r < ROUNDS; ++r) {
        int pos = r * 64 + lane;
        bool act = pos < NP;
        int pp = act ? pos : 0;
        int oh = pp / WO, ow = pp % WO;
        const float* sl = lds + (oh * S) * PW + ow * S;
        const float* wc = wp;
        float aC = 0.f, aL = 0.f, aH = 0.f;
        for (int c = 0; c < CC; ++c) {
            #pragma unroll
            for (int kh = 0; kh < K; ++kh)
                #pragma unroll
                for (int kw = 0; kw < K; ++kw) {
                    float w = wc[kh * K + kw];
                    tap16(w, sl[kh * PW + kw], sl[PP + kh * PW + kw],
                          sl[2 * PP + kh * PW + kw], aC, aL, aH);
                }
            sl += 3 * PP; wc += K * K;
        }
        if (act) {
            size_t N = (size_t)B * O * NP;
            size_t oidx = ((size_t)b * O + o) * NP + pos;
            OUT[oidx] = aC; OUT[N + oidx] = aL; OUT[2 * N + oidx] = aH;
        }
    }
}

// maxpool 3x3 s2 + rt8 (monotonic commute). Standard layouts both sides.
__global__ void pool_rt8(const float* __restrict__ in, float* __restrict__ out,
                         int BC, int Hin, int Win, int Ho, int Wo,
                         int n_in, int n_out)
{
    int idx = blockIdx.x * blockDim.x + threadIdx.x;
    int per = BC * Ho * Wo;
    if (idx >= 3 * per) return;
    int tsel = idx / per; int r = idx - tsel * per;
    int ow = r % Wo; int t2 = r / Wo;
    int oh = t2 % Ho; int bc = t2 / Ho;
    const float* ip = in + (size_t)tsel * n_in + (size_t)bc * Hin * Win;
    int ih0 = oh * 2, iw0 = ow * 2;
    float m = -INFINITY;
    #pragma unroll
    for (int i = 0; i < 3; ++i)
        #pragma unroll
        for (int j = 0; j < 3; ++j)
            m = fmaxf(m, ip[(ih0 + i) * Win + (iw0 + j)]);
    out[(size_t)tsel * n_out + r] = rt8(m);
}

// conv2: block = (chunk,b,oh), 256 threads, thread = o. b128 LDS row loads.
template<int CC>
__launch_bounds__(256)
__global__ void conv2_kernel(const float* __restrict__ IN, const float* __restrict__ WT,
                             float* __restrict__ P, int nin)
{
    constexpr int B = 16, Cin = 96, O = 256;
    constexpr size_t N = (size_t)B * O * 49;
    __shared__ __align__(16) float slab[CC * 180];  // [c][tsel(3)][r(5)][col(12)]
    int x = blockIdx.x;
    int oh   = x % 7;
    int b    = (x / 7) % B;
    int chunk = x / (7 * B);
    int c0 = chunk * CC;
    int tid = threadIdx.x;

    for (int i = tid; i < CC * 180; i += 256) {
        int c = i / 180; int rem = i - c * 180;
        int tsel = rem / 60; int rr = rem - tsel * 60;
        int r = rr / 12, col = rr - r * 12;
        int ih = oh + r - 2, iw = col - 2;
        float v = 0.f;
        if (col < 11 && (unsigned)ih < 7u && (unsigned)iw < 7u)
            v = IN[(size_t)tsel * nin + ((size_t)b * Cin + c0 + c) * 49 + ih * 7 + iw];
        slab[i] = v;
    }
    __syncthreads();

    int o = tid;
    float aC[7], aL[7], aH[7];
    #pragma unroll
    for (int u = 0; u < 7; ++u) { aC[u] = 0.f; aL[u] = 0.f; aH[u] = 0.f; }

    for (int c = 0; c < CC; ++c) {
        const float* wp = WT + (size_t)((c0 + c) * 25) * O + o;
        float w[25];
        #pragma unroll
        for (int t = 0; t < 25; ++t) w[t] = wp[(size_t)t * O];
        const float* sb = slab + c * 180;
        #pragma unroll
        for (int r = 0; r < 5; ++r) {
            float X[12], L[12], U[12];
            const float4* px = (const float4*)(sb + r * 12);
            const float4* pl = (const float4*)(sb + 60 + r * 12);
            const float4* pu = (const float4*)(sb + 120 + r * 12);
            ((float4*)X)[0] = px[0]; ((float4*)X)[1] = px[1]; ((float4*)X)[2] = px[2];
            ((float4*)L)[0] = pl[0]; ((float4*)L)[1] = pl[1]; ((float4*)L)[2] = pl[2];
            ((float4*)U)[0] = pu[0]; ((float4*)U)[1] = pu[1]; ((float4*)U)[2] = pu[2];
            #pragma unroll
            for (int ow = 0; ow < 7; ++ow)
                #pragma unroll
                for (int kw = 0; kw < 5; ++kw)
                    tap16(w[r * 5 + kw], X[ow + kw], L[ow + kw], U[ow + kw],
                          aC[ow], aL[ow], aH[ow]);
        }
    }

    float* Pc = P + (size_t)chunk * 3 * N;
    size_t rowbase = ((size_t)(b * 7 + oh) * 7) * O + o;
    #pragma unroll
    for (int u = 0; u < 7; ++u) {
        Pc[rowbase + (size_t)u * O]         = aC[u];
        Pc[N + rowbase + (size_t)u * O]     = aL[u];
        Pc[2 * N + rowbase + (size_t)u * O] = aH[u];
    }
}

// Fused conv2-combine + pool2 + rt8. Output D pos-major: [tsel][b][pos(9)][256].
__global__ void comb2_pool2(const float* __restrict__ P, float* __restrict__ D)
{
    constexpr int B = 16, O = 256, NCH = 16;
    constexpr size_t N = (size_t)B * O * 49;
    int idx = blockIdx.x * blockDim.x + threadIdx.x;
    if (idx >= 3 * B * 9 * O) return;
    int o = idx & 255; int t = idx >> 8;
    int pos = t % 9; t /= 9;
    int b = t % B; int tsel = t / B;
    int ph = pos / 3, pw = pos % 3;
    float m = 0.f;  // sums are >= 0
    #pragma unroll
    for (int i = 0; i < 3; ++i)
        #pragma unroll
        for (int j = 0; j < 3; ++j) {
            int sp = (ph * 2 + i) * 7 + (pw * 2 + j);
            size_t base = (size_t)tsel * N + ((size_t)b * 49 + sp) * O + o;
            float s = 0.f;
            #pragma unroll
            for (int ch = 0; ch < NCH; ++ch) s += P[(size_t)ch * 3 * N + base];
            m = fmaxf(m, s);
        }
    D[idx] = rt8(m);
}

// conv3/4/5: block = (chunk,b), thread = o. Input pos-major [tsel][b][pos][Cin].
template<int CC>
__launch_bounds__(384)
__global__ void conv3x3_kernel(const float* __restrict__ IN, const float* __restrict__ WT,
                               float* __restrict__ P, int B, int Cin, int O)
{
    __shared__ float slab[CC * 75];  // [c][tsel][iy(5)][ix(5)]
    int x = blockIdx.x;
    int b = x % B;
    int chunk = x / B;
    int c0 = chunk * CC;
    int tid = threadIdx.x;

    for (int i = tid; i < CC * 75; i += blockDim.x) {
        int c = i / 75; int rem = i - c * 75;
        int tsel = rem / 25; int rr = rem - tsel * 25;
        int iy = rr / 5, ix = rr - iy * 5;
        int ih = iy - 1, iw = ix - 1;
        float v = 0.f;
        if ((unsigned)ih < 3u && (unsigned)iw < 3u)
            v = IN[(((size_t)tsel * B + b) * 9 + (ih * 3 + iw)) * Cin + (c0 + c)];
        slab[i] = v;
    }
    __syncthreads();

    int o = tid;
    float aC[9], aL[9], aH[9];
    #pragma unroll
    for (int u = 0; u < 9; ++u) { aC[u] = 0.f; aL[u] = 0.f; aH[u] = 0.f; }

    for (int c = 0; c < CC; ++c) {
        const float* wp = WT + (size_t)((c0 + c) * 9) * O + o;
        float w[9];
        #pragma unroll
        for (int t = 0; t < 9; ++t) w[t] = wp[(size_t)t * O];
        const float* sb = slab + c * 75;
        #pragma unroll
        for (int py = 0; py < 3; ++py)
            #pragma unroll
            for (int px = 0; px < 3; ++px)
                #pragma unroll
                for (int ky = 0; ky < 3; ++ky)
                    #pragma unroll
                    for (int kx = 0; kx < 3; ++kx) {
                        int iy = py + ky, ix = px + kx;
                        tap16(w[ky * 3 + kx], sb[iy * 5 + ix], sb[25 + iy * 5 + ix],
                              sb[50 + iy * 5 + ix],
                              aC[py * 3 + px], aL[py * 3 + px], aH[py * 3 + px]);
                    }
    }

    size_t N = (size_t)B * O * 9;
    float* Pc = P + (size_t)chunk * 3 * N;
    size_t base = ((size_t)b * 9) * O + o;
    #pragma unroll
    for (int u = 0; u < 9; ++u) {
        Pc[base + (size_t)u * O]         = aC[u];
        Pc[N + base + (size_t)u * O]     = aL[u];
        Pc[2 * N + base + (size_t)u * O] = aH[u];
    }
}

// Pure coalesced sum+rt8 (layouts identical in and out, pos-major).
__global__ void conv_comb_flat(const float* __restrict__ P, float* __restrict__ OUT,
                               size_t N3, int NCH)
{
    size_t idx = (size_t)blockIdx.x * blockDim.x + threadIdx.x;
    if (idx >= N3) return;
    float s = 0.f;
    for (int ch = 0; ch < NCH; ++ch) s += P[(size_t)ch * N3 + idx];
    OUT[idx] = rt8(s);
}

// conv5 combine -> standard [tsel][b][O][9] layout for fc1.
__global__ void comb5_std(const float* __restrict__ P, float* __restrict__ G, int NCH)
{
    constexpr int B = 16, O = 256;
    constexpr size_t N = (size_t)B * O * 9;
    size_t idx = (size_t)blockIdx.x * blockDim.x + threadIdx.x;
    if (idx >= 3 * N) return;
    float s = 0.f;
    for (int ch = 0; ch < NCH; ++ch) s += P[(size_t)ch * 3 * N + idx];
    int o = (int)(idx % O); size_t t = idx / O;
    int pos = (int)(t % 9); t /= 9;
    int b = (int)(t % B); int tsel = (int)(t / B);
    G[(size_t)tsel * N + ((size_t)b * O + o) * 9 + pos] = rt8(s);
}

// fc1/fc2: wave per (b,o); float4 coalesced; butterfly reduce; relu.
__launch_bounds__(256)
__global__ void fc_gemv(const float* __restrict__ IC, const float* __restrict__ IL,
                        const float* __restrict__ IU, const float* __restrict__ W,
                        float* __restrict__ OUT, int B, int In, int Out)
{
    int gw = (int)((blockIdx.x * blockDim.x + threadIdx.x) >> 6);
    int lane = threadIdx.x & 63;
    if (gw >= B * Out) return;
    int o = gw % Out, b = gw / Out;
    const float4* wr = (const float4*)(W  + (size_t)o * In);
    const float4* cr = (const float4*)(IC + (size_t)b * In);
    const float4* lr = (const float4*)(IL + (size_t)b * In);
    const float4* ur = (const float4*)(IU + (size_t)b * In);
    int In4 = In >> 2;
    float sc = 0.f, sm = 0.f, sr = 0.f;
    for (int i = lane; i < In4; i += 64) {
        float4 w4 = wr[i], c4 = cr[i], l4 = lr[i], u4 = ur[i];
        sc = fmaf(c4.x, w4.x, sc); sc = fmaf(c4.y, w4.y, sc);
        sc = fmaf(c4.z, w4.z, sc); sc = fmaf(c4.w, w4.w, sc);
        sm = fmaf((l4.x + u4.x) * 0.5f, w4.x, sm);
        sm = fmaf((l4.y + u4.y) * 0.5f, w4.y, sm);
        sm = fmaf((l4.z + u4.z) * 0.5f, w4.z, sm);
        sm = fmaf((l4.w + u4.w) * 0.5f, w4.w, sm);
        sr = fmaf((u4.x - l4.x) * 0.5f, fabsf(w4.x), sr);
        sr = fmaf((u4.y - l4.y) * 0.5f, fabsf(w4.y), sr);
        sr = fmaf((u4.z - l4.z) * 0.5f, fabsf(w4.z), sr);
        sr = fmaf((u4.w - l4.w) * 0.5f, fabsf(w4.w), sr);
    }
    #pragma unroll
    for (int off = 32; off; off >>= 1) {
        sc += __shfl_xor(sc, off);
        sm += __shfl_xor(sm, off);
        sr += __shfl_xor(sr, off);
    }
    if (lane == 0) {
        size_t N = (size_t)B * Out;
        size_t idx = (size_t)b * Out + o;
        OUT[idx]         = fmaxf(sc, 0.f);
        OUT[N + idx]     = fmaxf(sm - sr, 0.f);
        OUT[2 * N + idx] = fmaxf(sm + sr, 0.f);
    }
}

__global__ void bound_linear_kernel(
    const float* __restrict__ IC, const float* __restrict__ IL, const float* __restrict__ IU,
    const float* __restrict__ W, const float* __restrict__ bias,
    float* __restrict__ OC, float* __restrict__ OL, float* __restrict__ OU,
    int B, int In, int Out)
{
    int idx = blockIdx.x * blockDim.x + threadIdx.x;
    if (idx >= B * Out) return;
    int o = idx % Out, b = idx / Out;
    const float* wr = W  + (size_t)o * In;
    const float* cr = IC + (size_t)b * In;
    const float* lr = IL + (size_t)b * In;
    const float* ur = IU + (size_t)b * In;
    float sc = 0.f, sm = 0.f, sr = 0.f;
    for (int i = 0; i < In; ++i) {
        float w = wr[i];
        sc = fmaf(cr[i], w, sc);
        sm = fmaf((lr[i] + ur[i]) * 0.5f, w, sm);
        sr = fmaf((ur[i] - lr[i]) * 0.5f, fabsf(w), sr);
    }
    float bb = bias[o]; sc += bb; sm += bb;
    OC[idx] = -sc; OL[idx] = -(sm - sr); OU[idx] = -(sm + sr);
}

extern "C" void kernel_launch(void* const* d_in, const int* in_sizes, int n_in,
                              void* d_out, int out_size, void* d_ws, size_t ws_size,
                              hipStream_t stream)
{
    const float* x   = (const float*)d_in[0];
    const float* lo  = (const float*)d_in[1];
    const float* hi  = (const float*)d_in[2];
    const float* w1  = (const float*)d_in[3];
    const float* w2  = (const float*)d_in[4];
    const float* w3  = (const float*)d_in[5];
    const float* w4  = (const float*)d_in[6];
    const float* w5  = (const float*)d_in[7];
    const float* fw1 = (const float*)d_in[8];
    const float* fw2 = (const float*)d_in[9];
    const float* fw3 = (const float*)d_in[10];
    const float* fb3 = (const float*)d_in[11];
    float* out = (float*)d_out;
    float* ws  = (float*)d_ws;

    const size_t n_c1 = 16u * 96 * 15 * 15;   // conv1 raw
    const size_t n_p1 = 16u * 96 * 7 * 7;
    const size_t n_d  = 16u * 256 * 9;        // pooled conv2, pos-major
    const size_t n_c3 = 16u * 384 * 9;
    const size_t n_c5 = 16u * 256 * 9;
    const size_t n_f1 = 16u * 1024;
    const size_t n_f2 = 16u * 512;

    float* A   = ws;                 // conv1 raw sums
    float* Bp  = A  + 3 * n_c1;      // pool1 out (standard layout)
    float* D   = Bp + 3 * n_p1;      // pooled conv2, pos-major
    float* E   = D  + 3 * n_d;       // conv3 out, pos-major
    float* F   = E  + 3 * n_c3;      // conv4 out, pos-major
    float* G   = F  + 3 * n_c3;      // conv5 out, standard layout
    float* H   = G  + 3 * n_c5;      // fc1 out
    float* I   = H  + 3 * n_f1;      // fc2 out
    float* WT2 = I  + 3 * n_f2;      // 614400
    float* WT3 = WT2 + 614400;       // 884736
    float* WT4 = WT3 + 884736;       // 1327104
    float* WT5 = WT4 + 1327104;      // 884736
    float* SP  = WT5 + 884736;       // partials: max 16*3*200704 = 9.63M floats

    const int BS = 256;
    auto grid = [](size_t tot) { return dim3((unsigned)((tot + 255) / 256)); };

    wtrans4<<<4 * 38 + 6 * 36 + 6 * 54 + 4 * 54, BS, 0, stream>>>(
        w2, w3, w4, w5, WT2, WT3, WT4, WT5);

    // conv1 (raw sums): [16,3,32,32] k7 s2 p2 -> [16,96,15,15]
    conv_a<7, 2, 2, 3, 32, 32, 15, 15><<<384, BS, 0, stream>>>(
        x, lo, hi, w1, A, 16, 3, 96, 24);
    // pool1 + rt8: 15 -> 7
    pool_rt8<<<grid(3 * n_p1), BS, 0, stream>>>(
        A, Bp, 16 * 96, 15, 15, 7, 7, (int)n_c1, (int)n_p1);
    // conv2: NCH=16, CC=6; 1792 blocks of 256
    conv2_kernel<6><<<16 * 16 * 7, 256, 0, stream>>>(Bp, WT2, SP, (int)n_p1);
    // fused combine + pool2 + rt8 -> D pos-major [tsel][b][9][256]
    comb2_pool2<<<grid(3 * n_d), BS, 0, stream>>>(SP, D);
    // conv3: Cin=256 O=384; NCH=32, CC=8
    conv3x3_kernel<8><<<32 * 16, 384, 0, stream>>>(D, WT3, SP, 16, 256, 384);
    conv_comb_flat<<<grid(3 * n_c3), BS, 0, stream>>>(SP, E, 3 * n_c3, 32);
    // conv4: Cin=384 O=384; NCH=48, CC=8
    conv3x3_kernel<8><<<48 * 16, 384, 0, stream>>>(E, WT4, SP, 16, 384, 384);
    conv_comb_flat<<<grid(3 * n_c3), BS, 0, stream>>>(SP, F, 3 * n_c3, 48);
    // conv5: Cin=384 O=256; NCH=48, CC=8
    conv3x3_kernel<8><<<48 * 16, 256, 0, stream>>>(F, WT5, SP, 16, 384, 256);
    comb5_std<<<grid(3 * n_c5), BS, 0, stream>>>(SP, G, 48);
    // fc1: 2304 -> 1024, relu
    fc_gemv<<<grid(16384u * 64), BS, 0, stream>>>(
        G, G + n_c5, G + 2 * n_c5, fw1, H, 16, 2304, 1024);
    // fc2: 1024 -> 512, relu
    fc_gemv<<<grid(8192u * 64), BS, 0, stream>>>(
        H, H + n_f1, H + 2 * n_f1, fw2, I, 16, 1024, 512);
    // fc3: 512 -> 10, +bias, negate+swap: out = [-c | -u | -l]
    bound_linear_kernel<<<grid(160), BS, 0, stream>>>(
        I, I + n_f2, I + 2 * n_f2, fw3, fb3,
        out, out + 320, out + 160, 16, 512, 10);
}

// Round 8
// 593.577 us; speedup vs baseline: 1.3651x; 1.1035x over previous
//
#include <hip/hip_runtime.h>
#include <math.h>

// ---------------------------------------------------------------------------
// NormDist (Lp, p=8) IBP AlexNet. Round 8: packed-FP32 (v_pk_*) via float2
// ext-vectors, pairing adjacent input channels. LDS slabs interleave channel
// parity so x-loads are ds_read_b64; weight transpose emits c-pair-interleaved
// layout so weight loads are per-lane b64 (coalesced). Accumulator halves are
// per-channel partials summed at store. lp8(d) = (sum d^8)^(1/8).
// ---------------------------------------------------------------------------

typedef float vf2 __attribute__((ext_vector_type(2)));

__device__ __forceinline__ float rt8(float s) { return sqrtf(sqrtf(sqrtf(s))); }

__device__ __forceinline__ void tap16(float w, float pc, float pl, float pu,
                                      float& aC, float& aL, float& aH)
{
    float a = pc - w; float a2 = a * a, a4 = a2 * a2; aC = fmaf(a4, a4, aC);
    float x = pl - w, y = pu - w;
    float dl = fmaxf(fmaxf(x, -y), 0.f);
    float e2 = dl * dl, e4 = e2 * e2; aL = fmaf(e4, e4, aL);
    float h2 = fmaxf(x * x, y * y);
    float h4 = h2 * h2; aH = fmaf(h4, h4, aH);
}

__device__ __forceinline__ void tap16v2(vf2 w, vf2 pc, vf2 pl, vf2 pu,
                                        vf2& aC, vf2& aL, vf2& aH)
{
    vf2 a = pc - w; vf2 a2 = a * a, a4 = a2 * a2;
    aC = __builtin_elementwise_fma(a4, a4, aC);
    vf2 x = pl - w, y = pu - w;
    vf2 zero = {0.f, 0.f};
    vf2 dl = __builtin_elementwise_max(__builtin_elementwise_max(x, -y), zero);
    vf2 e2 = dl * dl, e4 = e2 * e2;
    aL = __builtin_elementwise_fma(e4, e4, aL);
    vf2 h2 = __builtin_elementwise_max(x * x, y * y);
    vf2 h4 = h2 * h2;
    aH = __builtin_elementwise_fma(h4, h4, aH);
}

// Batched 64x64 LDS-tiled transpose of w2..w5 into c-pair-interleaved layout:
// T[((c/2)*KK + t) * (2*O) + o*2 + (c&1)] = W[o*CK + c*KK + t].
__launch_bounds__(256)
__global__ void wtrans4(const float* __restrict__ W2, const float* __restrict__ W3,
                        const float* __restrict__ W4, const float* __restrict__ W5,
                        float* __restrict__ T2, float* __restrict__ T3,
                        float* __restrict__ T4, float* __restrict__ T5)
{
    constexpr int nt2 = 4 * 38, nt3 = 6 * 36, nt4 = 6 * 54, nt5 = 4 * 54;
    int bid = blockIdx.x;
    const float* W; float* T; int O, CK, KK, t;
    if (bid < nt2)                   { W = W2; T = T2; O = 256; CK = 2400; KK = 25; t = bid; }
    else if (bid < nt2 + nt3)        { W = W3; T = T3; O = 384; CK = 2304; KK = 9; t = bid - nt2; }
    else if (bid < nt2 + nt3 + nt4)  { W = W4; T = T4; O = 384; CK = 3456; KK = 9; t = bid - nt2 - nt3; }
    else                             { W = W5; T = T5; O = 256; CK = 3456; KK = 9; t = bid - nt2 - nt3 - nt4; }
    int tilesC = (CK + 63) / 64;
    int to = t / tilesC, tc = t - to * tilesC;
    int o0 = to * 64, c0 = tc * 64;
    __shared__ float tile[64][65];
    int lane = threadIdx.x & 63, wv = threadIdx.x >> 6;
    #pragma unroll
    for (int i = 0; i < 16; ++i) {
        int row = wv + i * 4;
        int c = c0 + lane;
        tile[row][lane] = (c < CK) ? W[(size_t)(o0 + row) * CK + c] : 0.f;
    }
    __syncthreads();
    #pragma unroll
    for (int i = 0; i < 16; ++i) {
        int row = wv + i * 4;
        int ck = c0 + row;
        if (ck < CK) {
            int c = ck / KK, tt = ck - c * KK;
            T[(size_t)((c >> 1) * KK + tt) * (2 * O) + (size_t)(o0 + lane) * 2 + (c & 1)]
                = tile[lane][row];
        }
    }
}

// conv1 (wave = one o, lanes = positions). Writes RAW d^8 sums (rt8 in pool1).
template<int K, int S, int PAD, int CC, int HIN, int WIN, int HO, int WO>
__launch_bounds__(256)
__global__ void conv_a(const float* __restrict__ IC, const float* __restrict__ IL,
                       const float* __restrict__ IU, const float* __restrict__ W,
                       float* __restrict__ OUT, int B, int Cin, int O, int OG)
{
    constexpr int PH = (HO - 1) * S + K;
    constexpr int PW = (WO - 1) * S + K;
    constexpr int PP = PH * PW;
    constexpr int HW = HIN * WIN;
    constexpr int NP = HO * WO;
    constexpr int ROUNDS = (NP + 63) / 64;
    __shared__ float lds[CC * 3 * PP];

    int og = blockIdx.x % OG;
    int b  = (blockIdx.x / OG) % B;
    int tid = threadIdx.x;

    for (int i = tid; i < CC * 3 * PP; i += 256) lds[i] = 0.f;
    __syncthreads();
    for (int tsel = 0; tsel < 3; ++tsel) {
        const float* src = (tsel == 0 ? IC : (tsel == 1 ? IL : IU))
                         + (size_t)b * Cin * HW;
        for (int e = tid; e < CC * HW; e += 256) {
            int c = e / HW, p = e % HW;
            int pr = p / WIN, pw_ = p % WIN;
            lds[c * 3 * PP + tsel * PP + (pr + PAD) * PW + (pw_ + PAD)] = src[e];
        }
    }
    __syncthreads();

    int wave = tid >> 6, lane = tid & 63;
    int o = __builtin_amdgcn_readfirstlane(og * 4 + wave);
    const float* wp = W + (size_t)o * Cin * (K * K);

    for (int r = 0; r < ROUNDS; ++r) {
        int pos = r * 64 + lane;
        bool act = pos < NP;
        int pp = act ? pos : 0;
        int oh = pp / WO, ow = pp % WO;
        const float* sl = lds + (oh * S) * PW + ow * S;
        const float* wc = wp;
        float aC = 0.f, aL = 0.f, aH = 0.f;
        for (int c = 0; c < CC; ++c) {
            #pragma unroll
            for (int kh = 0; kh < K; ++kh)
                #pragma unroll
                for (int kw = 0; kw < K; ++kw) {
                    float w = wc[kh * K + kw];
                    tap16(w, sl[kh * PW + kw], sl[PP + kh * PW + kw],
                          sl[2 * PP + kh * PW + kw], aC, aL, aH);
                }
            sl += 3 * PP; wc += K * K;
        }
        if (act) {
            size_t N = (size_t)B * O * NP;
            size_t oidx = ((size_t)b * O + o) * NP + pos;
            OUT[oidx] = aC; OUT[N + oidx] = aL; OUT[2 * N + oidx] = aH;
        }
    }
}

// maxpool 3x3 s2 + rt8 (monotonic commute).
__global__ void pool_rt8(const float* __restrict__ in, float* __restrict__ out,
                         int BC, int Hin, int Win, int Ho, int Wo,
                         int n_in, int n_out)
{
    int idx = blockIdx.x * blockDim.x + threadIdx.x;
    int per = BC * Ho * Wo;
    if (idx >= 3 * per) return;
    int tsel = idx / per; int r = idx - tsel * per;
    int ow = r % Wo; int t2 = r / Wo;
    int oh = t2 % Ho; int bc = t2 / Ho;
    const float* ip = in + (size_t)tsel * n_in + (size_t)bc * Hin * Win;
    int ih0 = oh * 2, iw0 = ow * 2;
    float m = -INFINITY;
    #pragma unroll
    for (int i = 0; i < 3; ++i)
        #pragma unroll
        for (int j = 0; j < 3; ++j)
            m = fmaxf(m, ip[(ih0 + i) * Win + (iw0 + j)]);
    out[(size_t)tsel * n_out + r] = rt8(m);
}

// conv2: block = (chunk,b,oh), 256 threads, thread = o. Channel-pair packed.
// slab: [cp][tsel(3)][r(5)][col(12)][par(2)]
template<int CC>  // CC even
__launch_bounds__(256)
__global__ void conv2_kernel(const float* __restrict__ IN, const float* __restrict__ WT,
                             float* __restrict__ P, int nin)
{
    constexpr int B = 16, Cin = 96, O = 256;
    constexpr int CP = CC / 2;
    constexpr size_t N = (size_t)B * O * 49;
    __shared__ __align__(16) float slab[CP * 360];
    int x = blockIdx.x;
    int oh   = x % 7;
    int b    = (x / 7) % B;
    int chunk = x / (7 * B);
    int c0 = chunk * CC;
    int tid = threadIdx.x;

    for (int i = tid; i < CP * 360; i += 256) {
        int cp = i / 360; int rem = i - cp * 360;
        int tsel = rem / 120; int rr = rem - tsel * 120;
        int r = rr / 24; int cpar = rr - r * 24;
        int col = cpar >> 1, par = cpar & 1;
        int c = c0 + cp * 2 + par;
        int ih = oh + r - 2, iw = col - 2;
        float v = 0.f;
        if (col < 11 && (unsigned)ih < 7u && (unsigned)iw < 7u)
            v = IN[(size_t)tsel * nin + ((size_t)b * Cin + c) * 49 + ih * 7 + iw];
        slab[i] = v;
    }
    __syncthreads();

    int o = tid;
    vf2 aC2[7], aL2[7], aH2[7];
    vf2 zero = {0.f, 0.f};
    #pragma unroll
    for (int u = 0; u < 7; ++u) { aC2[u] = zero; aL2[u] = zero; aH2[u] = zero; }

    for (int cp = 0; cp < CP; ++cp) {
        const float* wp = WT + (size_t)((c0 / 2 + cp) * 25) * (2 * O) + 2 * o;
        const float* sb = slab + cp * 360;
        #pragma unroll
        for (int r = 0; r < 5; ++r) {
            vf2 wr[5];
            #pragma unroll
            for (int kw = 0; kw < 5; ++kw)
                wr[kw] = *(const vf2*)(wp + (size_t)(r * 5 + kw) * (2 * O));
            vf2 X[12], L[12], U[12];
            #pragma unroll
            for (int i2 = 0; i2 < 12; ++i2) {
                X[i2] = *(const vf2*)(sb + r * 24 + i2 * 2);
                L[i2] = *(const vf2*)(sb + 120 + r * 24 + i2 * 2);
                U[i2] = *(const vf2*)(sb + 240 + r * 24 + i2 * 2);
            }
            #pragma unroll
            for (int ow = 0; ow < 7; ++ow)
                #pragma unroll
                for (int kw = 0; kw < 5; ++kw)
                    tap16v2(wr[kw], X[ow + kw], L[ow + kw], U[ow + kw],
                            aC2[ow], aL2[ow], aH2[ow]);
        }
    }

    float* Pc = P + (size_t)chunk * 3 * N;
    size_t rowbase = ((size_t)(b * 7 + oh) * 7) * O + o;
    #pragma unroll
    for (int u = 0; u < 7; ++u) {
        Pc[rowbase + (size_t)u * O]         = aC2[u].x + aC2[u].y;
        Pc[N + rowbase + (size_t)u * O]     = aL2[u].x + aL2[u].y;
        Pc[2 * N + rowbase + (size_t)u * O] = aH2[u].x + aH2[u].y;
    }
}

// Fused conv2-combine + pool2 + rt8. Output D pos-major: [tsel][b][pos(9)][256].
__global__ void comb2_pool2(const float* __restrict__ P, float* __restrict__ D)
{
    constexpr int B = 16, O = 256, NCH = 16;
    constexpr size_t N = (size_t)B * O * 49;
    int idx = blockIdx.x * blockDim.x + threadIdx.x;
    if (idx >= 3 * B * 9 * O) return;
    int o = idx & 255; int t = idx >> 8;
    int pos = t % 9; t /= 9;
    int b = t % B; int tsel = t / B;
    int ph = pos / 3, pw = pos % 3;
    float m = 0.f;  // sums are >= 0
    #pragma unroll
    for (int i = 0; i < 3; ++i)
        #pragma unroll
        for (int j = 0; j < 3; ++j) {
            int sp = (ph * 2 + i) * 7 + (pw * 2 + j);
            size_t base = (size_t)tsel * N + ((size_t)b * 49 + sp) * O + o;
            float s = 0.f;
            #pragma unroll
            for (int ch = 0; ch < NCH; ++ch) s += P[(size_t)ch * 3 * N + base];
            m = fmaxf(m, s);
        }
    D[idx] = rt8(m);
}

// conv3/4/5: block = (chunk,b), thread = o. Channel-pair packed.
// slab: [cp][tsel(3)][p(25)][par(2)]; input pos-major [tsel][b][pos][Cin].
template<int CC>  // CC even
__launch_bounds__(384)
__global__ void conv3x3_kernel(const float* __restrict__ IN, const float* __restrict__ WT,
                               float* __restrict__ P, int B, int Cin, int O)
{
    constexpr int CP = CC / 2;
    __shared__ __align__(8) float slab[CP * 150];
    int x = blockIdx.x;
    int b = x % B;
    int chunk = x / B;
    int c0 = chunk * CC;
    int tid = threadIdx.x;

    for (int i = tid; i < CP * 150; i += blockDim.x) {
        int cp = i / 150; int rem = i - cp * 150;
        int tsel = rem / 50; int rr = rem - tsel * 50;
        int p = rr >> 1, par = rr & 1;
        int iy = p / 5, ix = p - iy * 5;
        int ih = iy - 1, iw = ix - 1;
        int c = c0 + cp * 2 + par;
        float v = 0.f;
        if ((unsigned)ih < 3u && (unsigned)iw < 3u)
            v = IN[(((size_t)tsel * B + b) * 9 + (ih * 3 + iw)) * Cin + c];
        slab[i] = v;
    }
    __syncthreads();

    int o = tid;
    vf2 aC2[9], aL2[9], aH2[9];
    vf2 zero = {0.f, 0.f};
    #pragma unroll
    for (int u = 0; u < 9; ++u) { aC2[u] = zero; aL2[u] = zero; aH2[u] = zero; }

    for (int cp = 0; cp < CP; ++cp) {
        const float* wp = WT + (size_t)((c0 / 2 + cp) * 9) * (2 * O) + 2 * o;
        vf2 w2[9];
        #pragma unroll
        for (int t = 0; t < 9; ++t) w2[t] = *(const vf2*)(wp + (size_t)t * (2 * O));
        const float* sb = slab + cp * 150;
        #pragma unroll
        for (int py = 0; py < 3; ++py)
            #pragma unroll
            for (int px = 0; px < 3; ++px)
                #pragma unroll
                for (int ky = 0; ky < 3; ++ky)
                    #pragma unroll
                    for (int kx = 0; kx < 3; ++kx) {
                        int p = (py + ky) * 5 + (px + kx);
                        tap16v2(w2[ky * 3 + kx],
                                *(const vf2*)(sb + p * 2),
                                *(const vf2*)(sb + 50 + p * 2),
                                *(const vf2*)(sb + 100 + p * 2),
                                aC2[py * 3 + px], aL2[py * 3 + px], aH2[py * 3 + px]);
                    }
    }

    size_t N = (size_t)B * O * 9;
    float* Pc = P + (size_t)chunk * 3 * N;
    size_t base = ((size_t)b * 9) * O + o;
    #pragma unroll
    for (int u = 0; u < 9; ++u) {
        Pc[base + (size_t)u * O]         = aC2[u].x + aC2[u].y;
        Pc[N + base + (size_t)u * O]     = aL2[u].x + aL2[u].y;
        Pc[2 * N + base + (size_t)u * O] = aH2[u].x + aH2[u].y;
    }
}

// Pure coalesced sum+rt8 (layout-preserving, pos-major).
__global__ void conv_comb_flat(const float* __restrict__ P, float* __restrict__ OUT,
                               size_t N3, int NCH)
{
    size_t idx = (size_t)blockIdx.x * blockDim.x + threadIdx.x;
    if (idx >= N3) return;
    float s = 0.f;
    for (int ch = 0; ch < NCH; ++ch) s += P[(size_t)ch * N3 + idx];
    OUT[idx] = rt8(s);
}

// conv5 combine -> standard [tsel][b][O][9] layout for fc1.
__global__ void comb5_std(const float* __restrict__ P, float* __restrict__ G, int NCH)
{
    constexpr int B = 16, O = 256;
    constexpr size_t N = (size_t)B * O * 9;
    size_t idx = (size_t)blockIdx.x * blockDim.x + threadIdx.x;
    if (idx >= 3 * N) return;
    float s = 0.f;
    for (int ch = 0; ch < NCH; ++ch) s += P[(size_t)ch * 3 * N + idx];
    int o = (int)(idx % O); size_t t = idx / O;
    int pos = (int)(t % 9); t /= 9;
    int b = (int)(t % B); int tsel = (int)(t / B);
    G[(size_t)tsel * N + ((size_t)b * O + o) * 9 + pos] = rt8(s);
}

// fc1/fc2: wave per (b,o); float4 coalesced; butterfly reduce; relu.
__launch_bounds__(256)
__global__ void fc_gemv(const float* __restrict__ IC, const float* __restrict__ IL,
                        const float* __restrict__ IU, const float* __restrict__ W,
                        float* __restrict__ OUT, int B, int In, int Out)
{
    int gw = (int)((blockIdx.x * blockDim.x + threadIdx.x) >> 6);
    int lane = threadIdx.x & 63;
    if (gw >= B * Out) return;
    int o = gw % Out, b = gw / Out;
    const float4* wr = (const float4*)(W  + (size_t)o * In);
    const float4* cr = (const float4*)(IC + (size_t)b * In);
    const float4* lr = (const float4*)(IL + (size_t)b * In);
    const float4* ur = (const float4*)(IU + (size_t)b * In);
    int In4 = In >> 2;
    float sc = 0.f, sm = 0.f, sr = 0.f;
    for (int i = lane; i < In4; i += 64) {
        float4 w4 = wr[i], c4 = cr[i], l4 = lr[i], u4 = ur[i];
        sc = fmaf(c4.x, w4.x, sc); sc = fmaf(c4.y, w4.y, sc);
        sc = fmaf(c4.z, w4.z, sc); sc = fmaf(c4.w, w4.w, sc);
        sm = fmaf((l4.x + u4.x) * 0.5f, w4.x, sm);
        sm = fmaf((l4.y + u4.y) * 0.5f, w4.y, sm);
        sm = fmaf((l4.z + u4.z) * 0.5f, w4.z, sm);
        sm = fmaf((l4.w + u4.w) * 0.5f, w4.w, sm);
        sr = fmaf((u4.x - l4.x) * 0.5f, fabsf(w4.x), sr);
        sr = fmaf((u4.y - l4.y) * 0.5f, fabsf(w4.y), sr);
        sr = fmaf((u4.z - l4.z) * 0.5f, fabsf(w4.z), sr);
        sr = fmaf((u4.w - l4.w) * 0.5f, fabsf(w4.w), sr);
    }
    #pragma unroll
    for (int off = 32; off; off >>= 1) {
        sc += __shfl_xor(sc, off);
        sm += __shfl_xor(sm, off);
        sr += __shfl_xor(sr, off);
    }
    if (lane == 0) {
        size_t N = (size_t)B * Out;
        size_t idx = (size_t)b * Out + o;
        OUT[idx]         = fmaxf(sc, 0.f);
        OUT[N + idx]     = fmaxf(sm - sr, 0.f);
        OUT[2 * N + idx] = fmaxf(sm + sr, 0.f);
    }
}

__global__ void bound_linear_kernel(
    const float* __restrict__ IC, const float* __restrict__ IL, const float* __restrict__ IU,
    const float* __restrict__ W, const float* __restrict__ bias,
    float* __restrict__ OC, float* __restrict__ OL, float* __restrict__ OU,
    int B, int In, int Out)
{
    int idx = blockIdx.x * blockDim.x + threadIdx.x;
    if (idx >= B * Out) return;
    int o = idx % Out, b = idx / Out;
    const float* wr = W  + (size_t)o * In;
    const float* cr = IC + (size_t)b * In;
    const float* lr = IL + (size_t)b * In;
    const float* ur = IU + (size_t)b * In;
    float sc = 0.f, sm = 0.f, sr = 0.f;
    for (int i = 0; i < In; ++i) {
        float w = wr[i];
        sc = fmaf(cr[i], w, sc);
        sm = fmaf((lr[i] + ur[i]) * 0.5f, w, sm);
        sr = fmaf((ur[i] - lr[i]) * 0.5f, fabsf(w), sr);
    }
    float bb = bias[o]; sc += bb; sm += bb;
    OC[idx] = -sc; OL[idx] = -(sm - sr); OU[idx] = -(sm + sr);
}

extern "C" void kernel_launch(void* const* d_in, const int* in_sizes, int n_in,
                              void* d_out, int out_size, void* d_ws, size_t ws_size,
                              hipStream_t stream)
{
    const float* x   = (const float*)d_in[0];
    const float* lo  = (const float*)d_in[1];
    const float* hi  = (const float*)d_in[2];
    const float* w1  = (const float*)d_in[3];
    const float* w2  = (const float*)d_in[4];
    const float* w3  = (const float*)d_in[5];
    const float* w4  = (const float*)d_in[6];
    const float* w5  = (const float*)d_in[7];
    const float* fw1 = (const float*)d_in[8];
    const float* fw2 = (const float*)d_in[9];
    const float* fw3 = (const float*)d_in[10];
    const float* fb3 = (const float*)d_in[11];
    float* out = (float*)d_out;
    float* ws  = (float*)d_ws;

    const size_t n_c1 = 16u * 96 * 15 * 15;   // conv1 raw
    const size_t n_p1 = 16u * 96 * 7 * 7;
    const size_t n_d  = 16u * 256 * 9;        // pooled conv2, pos-major
    const size_t n_c3 = 16u * 384 * 9;
    const size_t n_c5 = 16u * 256 * 9;
    const size_t n_f1 = 16u * 1024;
    const size_t n_f2 = 16u * 512;

    float* A   = ws;                 // conv1 raw sums
    float* Bp  = A  + 3 * n_c1;      // pool1 out (standard layout)
    float* D   = Bp + 3 * n_p1;      // pooled conv2, pos-major
    float* E   = D  + 3 * n_d;       // conv3 out, pos-major
    float* F   = E  + 3 * n_c3;      // conv4 out, pos-major
    float* G   = F  + 3 * n_c3;      // conv5 out, standard layout
    float* H   = G  + 3 * n_c5;      // fc1 out
    float* I   = H  + 3 * n_f1;      // fc2 out
    float* WT2 = I  + 3 * n_f2;      // 614400
    float* WT3 = WT2 + 614400;       // 884736
    float* WT4 = WT3 + 884736;       // 1327104
    float* WT5 = WT4 + 1327104;      // 884736
    float* SP  = WT5 + 884736;       // partials: max 16*3*200704 = 9.63M floats

    const int BS = 256;
    auto grid = [](size_t tot) { return dim3((unsigned)((tot + 255) / 256)); };

    wtrans4<<<4 * 38 + 6 * 36 + 6 * 54 + 4 * 54, BS, 0, stream>>>(
        w2, w3, w4, w5, WT2, WT3, WT4, WT5);

    // conv1 (raw sums): [16,3,32,32] k7 s2 p2 -> [16,96,15,15]
    conv_a<7, 2, 2, 3, 32, 32, 15, 15><<<384, BS, 0, stream>>>(
        x, lo, hi, w1, A, 16, 3, 96, 24);
    // pool1 + rt8: 15 -> 7
    pool_rt8<<<grid(3 * n_p1), BS, 0, stream>>>(
        A, Bp, 16 * 96, 15, 15, 7, 7, (int)n_c1, (int)n_p1);
    // conv2: NCH=16, CC=6; 1792 blocks of 256
    conv2_kernel<6><<<16 * 16 * 7, 256, 0, stream>>>(Bp, WT2, SP, (int)n_p1);
    // fused combine + pool2 + rt8 -> D pos-major [tsel][b][9][256]
    comb2_pool2<<<grid(3 * n_d), BS, 0, stream>>>(SP, D);
    // conv3: Cin=256 O=384; NCH=32, CC=8
    conv3x3_kernel<8><<<32 * 16, 384, 0, stream>>>(D, WT3, SP, 16, 256, 384);
    conv_comb_flat<<<grid(3 * n_c3), BS, 0, stream>>>(SP, E, 3 * n_c3, 32);
    // conv4: Cin=384 O=384; NCH=48, CC=8
    conv3x3_kernel<8><<<48 * 16, 384, 0, stream>>>(E, WT4, SP, 16, 384, 384);
    conv_comb_flat<<<grid(3 * n_c3), BS, 0, stream>>>(SP, F, 3 * n_c3, 48);
    // conv5: Cin=384 O=256; NCH=48, CC=8
    conv3x3_kernel<8><<<48 * 16, 256, 0, stream>>>(F, WT5, SP, 16, 384, 256);
    comb5_std<<<grid(3 * n_c5), BS, 0, stream>>>(SP, G, 48);
    // fc1: 2304 -> 1024, relu
    fc_gemv<<<grid(16384u * 64), BS, 0, stream>>>(
        G, G + n_c5, G + 2 * n_c5, fw1, H, 16, 2304, 1024);
    // fc2: 1024 -> 512, relu
    fc_gemv<<<grid(8192u * 64), BS, 0, stream>>>(
        H, H + n_f1, H + 2 * n_f1, fw2, I, 16, 1024, 512);
    // fc3: 512 -> 10, +bias, negate+swap: out = [-c | -u | -l]
    bound_linear_kernel<<<grid(160), BS, 0, stream>>>(
        I, I + n_f2, I + 2 * n_f2, fw3, fb3,
        out, out + 320, out + 160, 16, 512, 10);
}

// Round 10
// 582.545 us; speedup vs baseline: 1.3910x; 1.0189x over previous
//
#include <hip/hip_runtime.h>
#include <math.h>

// ---------------------------------------------------------------------------
// NormDist (Lp, p=8) IBP AlexNet. Round 10 = Round 9 fusion pass + conv1
// geometry fix (stride-2 padded slab is 35x35=1225, not 21x21; round 9's
// wrong extent scrambled conv1 and blew up the bound chains).
//  - prep kernel = batched weight transpose + conv1 (bid-routed).
//  - pool1+rt8 fused into conv2 staging; combine+pool2 fused; conv-combines
//    fused into conv4/conv5 staging. 10 kernel launches.
// HW model: fp32 VALU = 2 FLOP/lane/cy (pk-f32 saves issue slots/VGPR only).
// lp8(d) = (sum d^8)^(1/8); relu after conv = no-op (norms >= 0).
// ---------------------------------------------------------------------------

typedef float vf2 __attribute__((ext_vector_type(2)));

__device__ __forceinline__ float rt8(float s) { return sqrtf(sqrtf(sqrtf(s))); }

__device__ __forceinline__ void tap16(float w, float pc, float pl, float pu,
                                      float& aC, float& aL, float& aH)
{
    float a = pc - w; float a2 = a * a, a4 = a2 * a2; aC = fmaf(a4, a4, aC);
    float x = pl - w, y = pu - w;
    float dl = fmaxf(fmaxf(x, -y), 0.f);
    float e2 = dl * dl, e4 = e2 * e2; aL = fmaf(e4, e4, aL);
    float h2 = fmaxf(x * x, y * y);
    float h4 = h2 * h2; aH = fmaf(h4, h4, aH);
}

__device__ __forceinline__ void tap16v2(vf2 w, vf2 pc, vf2 pl, vf2 pu,
                                        vf2& aC, vf2& aL, vf2& aH)
{
    vf2 a = pc - w; vf2 a2 = a * a, a4 = a2 * a2;
    aC = __builtin_elementwise_fma(a4, a4, aC);
    vf2 x = pl - w, y = pu - w;
    vf2 zero = {0.f, 0.f};
    vf2 dl = __builtin_elementwise_max(__builtin_elementwise_max(x, -y), zero);
    vf2 e2 = dl * dl, e4 = e2 * e2;
    aL = __builtin_elementwise_fma(e4, e4, aL);
    vf2 h2 = __builtin_elementwise_max(x * x, y * y);
    vf2 h4 = h2 * h2;
    aH = __builtin_elementwise_fma(h4, h4, aH);
}

// prep: bid < 908 -> 64x64 LDS-tiled transpose of w2..w5 into c-pair layout
// T[((c/2)*KK+t)*(2*O) + o*2 + (c&1)]; else conv1 (round-split, 1536 blocks).
__launch_bounds__(256)
__global__ void prep_kernel(const float* __restrict__ W2, const float* __restrict__ W3,
                            const float* __restrict__ W4, const float* __restrict__ W5,
                            float* __restrict__ T2, float* __restrict__ T3,
                            float* __restrict__ T4, float* __restrict__ T5,
                            const float* __restrict__ IC, const float* __restrict__ IL,
                            const float* __restrict__ IU, const float* __restrict__ W1,
                            float* __restrict__ A)
{
    constexpr int nt2 = 152, nt3 = 216, nt4 = 324, nt5 = 216;
    constexpr int NTW = nt2 + nt3 + nt4 + nt5;  // 908
    // conv1 padded slab: PH=PW=(15-1)*2+7=35 -> PP=1225; 3 ch * 3 tensors.
    __shared__ float u[3 * 3 * 1225];           // 11025 >= 64*65=4160 (transpose)
    int bid = blockIdx.x;
    int tid = threadIdx.x;

    if (bid < NTW) {
        const float* W; float* T; int O, CK, KK, t;
        if (bid < nt2)                  { W = W2; T = T2; O = 256; CK = 2400; KK = 25; t = bid; }
        else if (bid < nt2 + nt3)       { W = W3; T = T3; O = 384; CK = 2304; KK = 9; t = bid - nt2; }
        else if (bid < nt2 + nt3 + nt4) { W = W4; T = T4; O = 384; CK = 3456; KK = 9; t = bid - nt2 - nt3; }
        else                            { W = W5; T = T5; O = 256; CK = 3456; KK = 9; t = bid - nt2 - nt3 - nt4; }
        int tilesC = (CK + 63) / 64;
        int to = t / tilesC, tc = t - to * tilesC;
        int o0 = to * 64, c0 = tc * 64;
        int lane = tid & 63, wv = tid >> 6;
        #pragma unroll
        for (int i = 0; i < 16; ++i) {
            int row = wv + i * 4;
            int c = c0 + lane;
            u[row * 65 + lane] = (c < CK) ? W[(size_t)(o0 + row) * CK + c] : 0.f;
        }
        __syncthreads();
        #pragma unroll
        for (int i = 0; i < 16; ++i) {
            int row = wv + i * 4;
            int ck = c0 + row;
            if (ck < CK) {
                int c = ck / KK, tt = ck - c * KK;
                T[(size_t)((c >> 1) * KK + tt) * (2 * O) + (size_t)(o0 + lane) * 2 + (c & 1)]
                    = u[lane * 65 + row];
            }
        }
        return;
    }

    // conv1: [16,3,32,32] k7 s2 p2 -> raw d^8 sums [3][16,96,15,15]
    constexpr int PP = 1225, PW = 35, HW = 1024;
    int t = bid - NTW;
    int og = t % 24; t /= 24;
    int b  = t % 16; int r = t / 16;   // r in [0,4)

    for (int i = tid; i < 3 * 3 * PP; i += 256) u[i] = 0.f;
    __syncthreads();
    for (int tsel = 0; tsel < 3; ++tsel) {
        const float* src = (tsel == 0 ? IC : (tsel == 1 ? IL : IU)) + (size_t)b * 3 * HW;
        for (int e = tid; e < 3 * HW; e += 256) {
            int c = e / HW, p = e % HW;
            int pr = p / 32, pw_ = p % 32;
            u[c * 3 * PP + tsel * PP + (pr + 2) * PW + (pw_ + 2)] = src[e];
        }
    }
    __syncthreads();

    int wave = tid >> 6, lane = tid & 63;
    int o = og * 4 + wave;
    const float* wp = W1 + (size_t)o * 147;
    int pos = r * 64 + lane;
    if (pos < 225) {
        int oh = pos / 15, ow = pos % 15;
        const float* sl = u + (oh * 2) * PW + ow * 2;
        float aC = 0.f, aL = 0.f, aH = 0.f;
        #pragma unroll
        for (int c = 0; c < 3; ++c) {
            #pragma unroll
            for (int kh = 0; kh < 7; ++kh)
                #pragma unroll
                for (int kw = 0; kw < 7; ++kw) {
                    float w = wp[c * 49 + kh * 7 + kw];
                    tap16(w, sl[kh * PW + kw], sl[PP + kh * PW + kw],
                          sl[2 * PP + kh * PW + kw], aC, aL, aH);
                }
            sl += 3 * PP;
        }
        size_t N = (size_t)16 * 96 * 225;
        size_t oi = ((size_t)b * 96 + o) * 225 + pos;
        A[oi] = aC; A[N + oi] = aL; A[2 * N + oi] = aH;
    }
}

// conv2: block=(chunk,b,oh), thread=o. Staging fuses pool1(3x3 s2)+rt8 from
// conv1 raw sums A [tsel][b*96+c][15*15]. slab: [cp][tsel][r(5)][col(12)][par(2)]
template<int CC>
__launch_bounds__(256)
__global__ void conv2_kernel(const float* __restrict__ A, const float* __restrict__ WT,
                             float* __restrict__ P)
{
    constexpr int B = 16, Cin = 96, O = 256;
    constexpr int CP = CC / 2;
    constexpr size_t N = (size_t)B * O * 49;
    constexpr size_t NA = (size_t)B * 96 * 225;
    __shared__ __align__(16) float slab[CP * 360];
    int x = blockIdx.x;
    int oh   = x % 7;
    int b    = (x / 7) % B;
    int chunk = x / (7 * B);
    int c0 = chunk * CC;
    int tid = threadIdx.x;

    for (int i = tid; i < CP * 360; i += 256) {
        int cp = i / 360; int rem = i - cp * 360;
        int tsel = rem / 120; int rr = rem - tsel * 120;
        int r = rr / 24; int cpar = rr - r * 24;
        int col = cpar >> 1, par = cpar & 1;
        int c = c0 + cp * 2 + par;
        int ih = oh + r - 2, iw = col - 2;
        float v = 0.f;
        if (col < 11 && (unsigned)ih < 7u && (unsigned)iw < 7u) {
            const float* ap = A + (size_t)tsel * NA + ((size_t)b * 96 + c) * 225
                            + (ih * 2) * 15 + iw * 2;
            float m = 0.f;  // sums >= 0
            #pragma unroll
            for (int pi = 0; pi < 3; ++pi)
                #pragma unroll
                for (int pj = 0; pj < 3; ++pj)
                    m = fmaxf(m, ap[pi * 15 + pj]);
            v = rt8(m);
        }
        slab[i] = v;
    }
    __syncthreads();

    int o = tid;
    vf2 aC2[7], aL2[7], aH2[7];
    vf2 zero = {0.f, 0.f};
    #pragma unroll
    for (int u = 0; u < 7; ++u) { aC2[u] = zero; aL2[u] = zero; aH2[u] = zero; }

    for (int cp = 0; cp < CP; ++cp) {
        const float* wp = WT + (size_t)((c0 / 2 + cp) * 25) * (2 * O) + 2 * o;
        const float* sb = slab + cp * 360;
        #pragma unroll
        for (int r = 0; r < 5; ++r) {
            vf2 wr[5];
            #pragma unroll
            for (int kw = 0; kw < 5; ++kw)
                wr[kw] = *(const vf2*)(wp + (size_t)(r * 5 + kw) * (2 * O));
            vf2 X[12], L[12], U[12];
            #pragma unroll
            for (int i2 = 0; i2 < 12; ++i2) {
                X[i2] = *(const vf2*)(sb + r * 24 + i2 * 2);
                L[i2] = *(const vf2*)(sb + 120 + r * 24 + i2 * 2);
                U[i2] = *(const vf2*)(sb + 240 + r * 24 + i2 * 2);
            }
            #pragma unroll
            for (int ow = 0; ow < 7; ++ow)
                #pragma unroll
                for (int kw = 0; kw < 5; ++kw)
                    tap16v2(wr[kw], X[ow + kw], L[ow + kw], U[ow + kw],
                            aC2[ow], aL2[ow], aH2[ow]);
        }
    }

    float* Pc = P + (size_t)chunk * 3 * N;
    size_t rowbase = ((size_t)(b * 7 + oh) * 7) * O + o;
    #pragma unroll
    for (int u = 0; u < 7; ++u) {
        Pc[rowbase + (size_t)u * O]         = aC2[u].x + aC2[u].y;
        Pc[N + rowbase + (size_t)u * O]     = aL2[u].x + aL2[u].y;
        Pc[2 * N + rowbase + (size_t)u * O] = aH2[u].x + aH2[u].y;
    }
}

// Fused conv2-combine + pool2 + rt8. Output D pos-major: [tsel][b][pos(9)][256].
__global__ void comb2_pool2(const float* __restrict__ P, float* __restrict__ D)
{
    constexpr int B = 16, O = 256, NCH = 16;
    constexpr size_t N = (size_t)B * O * 49;
    int idx = blockIdx.x * blockDim.x + threadIdx.x;
    if (idx >= 3 * B * 9 * O) return;
    int o = idx & 255; int t = idx >> 8;
    int pos = t % 9; t /= 9;
    int b = t % B; int tsel = t / B;
    int ph = pos / 3, pw = pos % 3;
    float m = 0.f;
    #pragma unroll
    for (int i = 0; i < 3; ++i)
        #pragma unroll
        for (int j = 0; j < 3; ++j) {
            int sp = (ph * 2 + i) * 7 + (pw * 2 + j);
            size_t base = (size_t)tsel * N + ((size_t)b * 49 + sp) * O + o;
            float s = 0.f;
            #pragma unroll
            for (int ch = 0; ch < NCH; ++ch) s += P[(size_t)ch * 3 * N + base];
            m = fmaxf(m, s);
        }
    D[idx] = rt8(m);
}

// conv3/4/5: block=(chunk,b), thread=o, channel-pair packed.
// NCHIN==0: input IN is final pos-major [tsel][b][pos][Cin].
// NCHIN>0:  input IN is partial sums (NCHIN chunks); staging does rt8(sum).
template<int CC, int NCHIN>
__launch_bounds__(384)
__global__ void conv3x3_kernel(const float* __restrict__ IN, const float* __restrict__ WT,
                               float* __restrict__ P, int B, int Cin, int O)
{
    constexpr int CP = CC / 2;
    __shared__ __align__(8) float slab[CP * 150];
    int x = blockIdx.x;
    int b = x % B;
    int chunk = x / B;
    int c0 = chunk * CC;
    int tid = threadIdx.x;

    size_t NN = (size_t)B * Cin * 9;
    for (int i = tid; i < CP * 150; i += blockDim.x) {
        int cp = i / 150; int rem = i - cp * 150;
        int tsel = rem / 50; int rr = rem - tsel * 50;
        int p = rr >> 1, par = rr & 1;
        int iy = p / 5, ix = p - iy * 5;
        int ih = iy - 1, iw = ix - 1;
        int c = c0 + cp * 2 + par;
        float v = 0.f;
        if ((unsigned)ih < 3u && (unsigned)iw < 3u) {
            size_t base = (size_t)tsel * NN + ((size_t)b * 9 + (ih * 3 + iw)) * Cin + c;
            if (NCHIN == 0) {
                v = IN[base];
            } else {
                float s = 0.f;
                #pragma unroll 8
                for (int ch = 0; ch < NCHIN; ++ch) s += IN[(size_t)ch * 3 * NN + base];
                v = rt8(s);
            }
        }
        slab[i] = v;
    }
    __syncthreads();

    int o = tid;
    vf2 aC2[9], aL2[9], aH2[9];
    vf2 zero = {0.f, 0.f};
    #pragma unroll
    for (int u = 0; u < 9; ++u) { aC2[u] = zero; aL2[u] = zero; aH2[u] = zero; }

    for (int cp = 0; cp < CP; ++cp) {
        const float* wp = WT + (size_t)((c0 / 2 + cp) * 9) * (2 * O) + 2 * o;
        vf2 w2[9];
        #pragma unroll
        for (int t = 0; t < 9; ++t) w2[t] = *(const vf2*)(wp + (size_t)t * (2 * O));
        const float* sb = slab + cp * 150;
        #pragma unroll
        for (int py = 0; py < 3; ++py)
            #pragma unroll
            for (int px = 0; px < 3; ++px)
                #pragma unroll
                for (int ky = 0; ky < 3; ++ky)
                    #pragma unroll
                    for (int kx = 0; kx < 3; ++kx) {
                        int p = (py + ky) * 5 + (px + kx);
                        tap16v2(w2[ky * 3 + kx],
                                *(const vf2*)(sb + p * 2),
                                *(const vf2*)(sb + 50 + p * 2),
                                *(const vf2*)(sb + 100 + p * 2),
                                aC2[py * 3 + px], aL2[py * 3 + px], aH2[py * 3 + px]);
                    }
    }

    size_t N = (size_t)B * O * 9;
    float* Pc = P + (size_t)chunk * 3 * N;
    size_t base = ((size_t)b * 9) * O + o;
    #pragma unroll
    for (int u = 0; u < 9; ++u) {
        Pc[base + (size_t)u * O]         = aC2[u].x + aC2[u].y;
        Pc[N + base + (size_t)u * O]     = aL2[u].x + aL2[u].y;
        Pc[2 * N + base + (size_t)u * O] = aH2[u].x + aH2[u].y;
    }
}

// conv5 combine -> standard [tsel][b][O][9] layout for fc1.
__global__ void comb5_std(const float* __restrict__ P, float* __restrict__ G, int NCH)
{
    constexpr int B = 16, O = 256;
    constexpr size_t N = (size_t)B * O * 9;
    size_t idx = (size_t)blockIdx.x * blockDim.x + threadIdx.x;
    if (idx >= 3 * N) return;
    float s = 0.f;
    for (int ch = 0; ch < NCH; ++ch) s += P[(size_t)ch * 3 * N + idx];
    int o = (int)(idx % O); size_t t = idx / O;
    int pos = (int)(t % 9); t /= 9;
    int b = (int)(t % B); int tsel = (int)(t / B);
    G[(size_t)tsel * N + ((size_t)b * O + o) * 9 + pos] = rt8(s);
}

// fc1/fc2: wave per (b,o); float4 coalesced; butterfly reduce; relu.
__launch_bounds__(256)
__global__ void fc_gemv(const float* __restrict__ IC, const float* __restrict__ IL,
                        const float* __restrict__ IU, const float* __restrict__ W,
                        float* __restrict__ OUT, int B, int In, int Out)
{
    int gw = (int)((blockIdx.x * blockDim.x + threadIdx.x) >> 6);
    int lane = threadIdx.x & 63;
    if (gw >= B * Out) return;
    int o = gw % Out, b = gw / Out;
    const float4* wr = (const float4*)(W  + (size_t)o * In);
    const float4* cr = (const float4*)(IC + (size_t)b * In);
    const float4* lr = (const float4*)(IL + (size_t)b * In);
    const float4* ur = (const float4*)(IU + (size_t)b * In);
    int In4 = In >> 2;
    float sc = 0.f, sm = 0.f, sr = 0.f;
    for (int i = lane; i < In4; i += 64) {
        float4 w4 = wr[i], c4 = cr[i], l4 = lr[i], u4 = ur[i];
        sc = fmaf(c4.x, w4.x, sc); sc = fmaf(c4.y, w4.y, sc);
        sc = fmaf(c4.z, w4.z, sc); sc = fmaf(c4.w, w4.w, sc);
        sm = fmaf((l4.x + u4.x) * 0.5f, w4.x, sm);
        sm = fmaf((l4.y + u4.y) * 0.5f, w4.y, sm);
        sm = fmaf((l4.z + u4.z) * 0.5f, w4.z, sm);
        sm = fmaf((l4.w + u4.w) * 0.5f, w4.w, sm);
        sr = fmaf((u4.x - l4.x) * 0.5f, fabsf(w4.x), sr);
        sr = fmaf((u4.y - l4.y) * 0.5f, fabsf(w4.y), sr);
        sr = fmaf((u4.z - l4.z) * 0.5f, fabsf(w4.z), sr);
        sr = fmaf((u4.w - l4.w) * 0.5f, fabsf(w4.w), sr);
    }
    #pragma unroll
    for (int off = 32; off; off >>= 1) {
        sc += __shfl_xor(sc, off);
        sm += __shfl_xor(sm, off);
        sr += __shfl_xor(sr, off);
    }
    if (lane == 0) {
        size_t N = (size_t)B * Out;
        size_t idx = (size_t)b * Out + o;
        OUT[idx]         = fmaxf(sc, 0.f);
        OUT[N + idx]     = fmaxf(sm - sr, 0.f);
        OUT[2 * N + idx] = fmaxf(sm + sr, 0.f);
    }
}

__global__ void bound_linear_kernel(
    const float* __restrict__ IC, const float* __restrict__ IL, const float* __restrict__ IU,
    const float* __restrict__ W, const float* __restrict__ bias,
    float* __restrict__ OC, float* __restrict__ OL, float* __restrict__ OU,
    int B, int In, int Out)
{
    int idx = blockIdx.x * blockDim.x + threadIdx.x;
    if (idx >= B * Out) return;
    int o = idx % Out, b = idx / Out;
    const float* wr = W  + (size_t)o * In;
    const float* cr = IC + (size_t)b * In;
    const float* lr = IL + (size_t)b * In;
    const float* ur = IU + (size_t)b * In;
    float sc = 0.f, sm = 0.f, sr = 0.f;
    for (int i = 0; i < In; ++i) {
        float w = wr[i];
        sc = fmaf(cr[i], w, sc);
        sm = fmaf((lr[i] + ur[i]) * 0.5f, w, sm);
        sr = fmaf((ur[i] - lr[i]) * 0.5f, fabsf(w), sr);
    }
    float bb = bias[o]; sc += bb; sm += bb;
    OC[idx] = -sc; OL[idx] = -(sm - sr); OU[idx] = -(sm + sr);
}

extern "C" void kernel_launch(void* const* d_in, const int* in_sizes, int n_in,
                              void* d_out, int out_size, void* d_ws, size_t ws_size,
                              hipStream_t stream)
{
    const float* x   = (const float*)d_in[0];
    const float* lo  = (const float*)d_in[1];
    const float* hi  = (const float*)d_in[2];
    const float* w1  = (const float*)d_in[3];
    const float* w2  = (const float*)d_in[4];
    const float* w3  = (const float*)d_in[5];
    const float* w4  = (const float*)d_in[6];
    const float* w5  = (const float*)d_in[7];
    const float* fw1 = (const float*)d_in[8];
    const float* fw2 = (const float*)d_in[9];
    const float* fw3 = (const float*)d_in[10];
    const float* fb3 = (const float*)d_in[11];
    float* out = (float*)d_out;
    float* ws  = (float*)d_ws;

    const size_t n_c1 = 16u * 96 * 225;       // conv1 raw
    const size_t n_d  = 16u * 256 * 9;        // pooled conv2, pos-major
    const size_t n_c5 = 16u * 256 * 9;
    const size_t n_f1 = 16u * 1024;
    const size_t n_f2 = 16u * 512;
    const size_t N3   = 16u * 384 * 9;        // conv3/conv4 output plane

    float* A   = ws;                 // conv1 raw sums: 3*n_c1
    float* D   = A  + 3 * n_c1;      // pooled conv2, pos-major: 3*n_d
    float* G   = D  + 3 * n_d;       // conv5 combined, standard: 3*n_c5
    float* H   = G  + 3 * n_c5;      // fc1 out
    float* I   = H  + 3 * n_f1;      // fc2 out
    float* WT2 = I  + 3 * n_f2;      // 614400
    float* WT3 = WT2 + 614400;       // 884736
    float* WT4 = WT3 + 884736;       // 1327104
    float* WT5 = WT4 + 1327104;      // 884736
    float* SP2 = WT5 + 884736;       // conv2 partials: 16*3*200704 = 9.63M
    float* SPa = SP2;                // conv3 partials alias (SP2 dead): 32*3*N3 = 5.31M
    float* SPc = SP2;                // conv5 partials alias (SPa dead): 48*3*n_c5
    float* SPb = SP2 + 32u * 3 * N3; // conv4 partials: 48*3*N3 = 7.96M

    const int BS = 256;
    auto grid = [](size_t tot) { return dim3((unsigned)((tot + 255) / 256)); };

    // prep: weight transposes (908 blocks) + conv1 (1536 blocks)
    prep_kernel<<<908 + 1536, BS, 0, stream>>>(
        w2, w3, w4, w5, WT2, WT3, WT4, WT5, x, lo, hi, w1, A);
    // conv2 (staging fuses pool1+rt8): NCH=16, CC=6; 1792 blocks
    conv2_kernel<6><<<16 * 16 * 7, 256, 0, stream>>>(A, WT2, SP2);
    // fused conv2-combine + pool2 + rt8 -> D pos-major
    comb2_pool2<<<grid(3 * n_d), BS, 0, stream>>>(SP2, D);
    // conv3: Cin=256 O=384; 32 chunks; direct staging from D
    conv3x3_kernel<8, 0><<<32 * 16, 384, 0, stream>>>(D, WT3, SPa, 16, 256, 384);
    // conv4: Cin=384 O=384; 48 chunks; staging = rt8(sum of 32 conv3 partials)
    conv3x3_kernel<8, 32><<<48 * 16, 384, 0, stream>>>(SPa, WT4, SPb, 16, 384, 384);
    // conv5: Cin=384 O=256; 48 chunks; staging = rt8(sum of 48 conv4 partials)
    conv3x3_kernel<8, 48><<<48 * 16, 256, 0, stream>>>(SPb, WT5, SPc, 16, 384, 256);
    // conv5 combine -> standard layout
    comb5_std<<<grid(3 * n_c5), BS, 0, stream>>>(SPc, G, 48);
    // fc1: 2304 -> 1024, relu
    fc_gemv<<<grid(16384u * 64), BS, 0, stream>>>(
        G, G + n_c5, G + 2 * n_c5, fw1, H, 16, 2304, 1024);
    // fc2: 1024 -> 512, relu
    fc_gemv<<<grid(8192u * 64), BS, 0, stream>>>(
        H, H + n_f1, H + 2 * n_f1, fw2, I, 16, 1024, 512);
    // fc3: 512 -> 10, +bias, negate+swap: out = [-c | -u | -l]
    bound_linear_kernel<<<grid(160), BS, 0, stream>>>(
        I, I + n_f2, I + 2 * n_f2, fw3, fb3,
        out, out + 320, out + 160, 16, 512, 10);
}